// Round 2
// baseline (2947.711 us; speedup 1.0000x reference)
//
#include <hip/hip_runtime.h>
#include <hip/hip_bf16.h>

// B=4, S=2048, D_MODEL=1024, H=16, E=64, M=8192 rows, bh = b*16+h (64)
// MFMA shape: mfma_f32_16x16x32_bf16.
//   A-frag: lane l holds A[m = l&15][k = (l>>4)*8 + j], j=0..7 (16B contiguous)
//   B-frag: lane l holds B[k = (l>>4)*8 + j][n = l&15]
//   C/D  : lane l holds D[row = (l>>4)*4 + r][col = l&15]   (verified layout)
// Precision: fp32 value = hi + mid + lo (3x bf16). 6 passes (hh,hm,mh,mm,hl,lh)
// reproduce the fp32 product to ~2^-24 relative.

typedef __attribute__((ext_vector_type(8))) short bf16x8;
typedef __attribute__((ext_vector_type(4))) float f32x4;

#define MFMA(a, b, c) __builtin_amdgcn_mfma_f32_16x16x32_bf16(a, b, c, 0, 0, 0)

__device__ __forceinline__ short f2bf(float x) {
    __hip_bfloat16 h = __float2bfloat16(x);
    union { __hip_bfloat16 h; short s; } u; u.h = h; return u.s;
}
__device__ __forceinline__ float bf2f(short s) {
    union { short s; __hip_bfloat16 h; } u; u.s = s; return __bfloat162float(u.h);
}
__device__ __forceinline__ void split3(float x, short& h, short& m, short& l) {
    h = f2bf(x); float r1 = x - bf2f(h);
    m = f2bf(r1); l = f2bf(r1 - bf2f(m));
}

// ---------------------------------------------------------------------------
// W_{Q,K,V} [16][1024][64] fp32 -> transposed 3-split bf16 [16][64 e][1024 d]
// ---------------------------------------------------------------------------
__global__ __launch_bounds__(256) void k_conv_w(
    const float* __restrict__ Wq, const float* __restrict__ Wk, const float* __restrict__ Wv,
    short* __restrict__ qh, short* __restrict__ qm, short* __restrict__ ql,
    short* __restrict__ kh, short* __restrict__ km, short* __restrict__ kl,
    short* __restrict__ vh, short* __restrict__ vm, short* __restrict__ vl)
{
    int gid = blockIdx.x * 256 + threadIdx.x;          // < 3 * 2^20
    int mat = gid >> 20; int idx = gid & 1048575;      // idx = h*65536 + d*64 + e
    int h = idx >> 16; int d = (idx >> 6) & 1023; int e = idx & 63;
    const float* W = (mat == 0) ? Wq : (mat == 1) ? Wk : Wv;
    short* th = (mat == 0) ? qh : (mat == 1) ? kh : vh;
    short* tm = (mat == 0) ? qm : (mat == 1) ? km : vm;
    short* tl = (mat == 0) ? ql : (mat == 1) ? kl : vl;
    float w = W[(size_t)mat * 0 + idx];
    short a, b, c; split3(w, a, b, c);
    size_t o = (size_t)h * 65536 + (size_t)e * 1024 + d;
    th[o] = a; tm[o] = b; tl[o] = c;
}

// W_O [1024 hd][1024 dm] fp32 -> woT [dm][hd] bf16 (single precision pass)
__global__ __launch_bounds__(256) void k_conv_wo(
    const float* __restrict__ wo, short* __restrict__ woT)
{
    int gid = blockIdx.x * 256 + threadIdx.x;          // < 2^20
    int hd = gid >> 10, dm = gid & 1023;
    woT[(size_t)dm * 1024 + hd] = f2bf(wo[gid]);
}

// ---------------------------------------------------------------------------
// QKV projection, 6-pass split MFMA. x converted to 3-split in registers.
// grid (48 = mat*16+h fastest for x L2 reuse, 128 m-tiles), 256 thr / 4 waves.
// Outputs: q,k 3-split [bh][s][64]; vT bf16 [bh][64 e][2048 s].
// ---------------------------------------------------------------------------
__global__ __launch_bounds__(256) void k_proj(
    const float* __restrict__ x,
    const short* __restrict__ wqh, const short* __restrict__ wqm, const short* __restrict__ wql,
    const short* __restrict__ wkh, const short* __restrict__ wkm, const short* __restrict__ wkl,
    const short* __restrict__ wvh, const short* __restrict__ wvm, const short* __restrict__ wvl,
    const float* __restrict__ bq, const float* __restrict__ bk, const float* __restrict__ bv,
    short* __restrict__ oqh, short* __restrict__ oqm, short* __restrict__ oql,
    short* __restrict__ okh, short* __restrict__ okm, short* __restrict__ okl,
    short* __restrict__ ovT)
{
    const int mh = blockIdx.x;                 // 0..47
    const int mat = mh >> 4, h = mh & 15;
    const int r0 = blockIdx.y * 64;
    const int tid = threadIdx.x, w = tid >> 6, lane = tid & 63;
    const int l15 = lane & 15, lhi = lane >> 4;
    const int rw = r0 + w * 16;

    const short* wh = (mat == 0) ? wqh : (mat == 1) ? wkh : wvh;
    const short* wm = (mat == 0) ? wqm : (mat == 1) ? wkm : wvm;
    const short* wl = (mat == 0) ? wql : (mat == 1) ? wkl : wvl;
    const float* bias = (mat == 0) ? bq : (mat == 1) ? bk : bv;

    f32x4 acc[4] = {};
    const size_t arow = (size_t)(rw + l15) * 1024;
    const size_t wbase = (size_t)h * 65536;

    for (int ch = 0; ch < 32; ++ch) {
        const int d0 = ch * 32 + lhi * 8;
        float4 xa = *(const float4*)&x[arow + d0];
        float4 xb = *(const float4*)&x[arow + d0 + 4];
        float xs[8] = {xa.x, xa.y, xa.z, xa.w, xb.x, xb.y, xb.z, xb.w};
        bf16x8 ah, am, al;
        #pragma unroll
        for (int j = 0; j < 8; ++j) {
            short sh, sm, sl; split3(xs[j], sh, sm, sl);
            ah[j] = sh; am[j] = sm; al[j] = sl;
        }
        #pragma unroll
        for (int nt = 0; nt < 4; ++nt) {
            const size_t bo = wbase + (size_t)(nt * 16 + l15) * 1024 + d0;
            bf16x8 bh2 = *(const bf16x8*)&wh[bo];
            bf16x8 bm2 = *(const bf16x8*)&wm[bo];
            bf16x8 bl2 = *(const bf16x8*)&wl[bo];
            acc[nt] = MFMA(ah, bh2, acc[nt]);
            acc[nt] = MFMA(ah, bm2, acc[nt]);
            acc[nt] = MFMA(am, bh2, acc[nt]);
            acc[nt] = MFMA(am, bm2, acc[nt]);
            acc[nt] = MFMA(ah, bl2, acc[nt]);
            acc[nt] = MFMA(al, bh2, acc[nt]);
        }
    }

    const int b = r0 >> 11;
    const int bh = b * 16 + h;
    #pragma unroll
    for (int nt = 0; nt < 4; ++nt) {
        const int e = nt * 16 + l15;
        const float bv_ = bias[h * 64 + e];
        #pragma unroll
        for (int r = 0; r < 4; ++r) {
            const int row = rw + lhi * 4 + r;
            const int s = row & 2047;
            float v = acc[nt][r] + bv_;
            if (mat < 2) {
                short sh, sm, sl; split3(v, sh, sm, sl);
                size_t o = ((size_t)bh * 2048 + s) * 64 + e;
                if (mat == 0) { oqh[o] = sh; oqm[o] = sm; oql[o] = sl; }
                else          { okh[o] = sh; okm[o] = sm; okl[o] = sl; }
            } else {
                ovT[((size_t)bh * 64 + e) * 2048 + s] = f2bf(v);
            }
        }
    }
}

// ---------------------------------------------------------------------------
// QK^T (6-pass split MFMA) + causal mask; writes RAW fp32 scores into the
// pattern buffer; computes per-row running max m and sum l (flash-style).
// grid (32 qt, 64 bh), 4 waves, wave = 16 q-rows.
// ---------------------------------------------------------------------------
__global__ __launch_bounds__(256) void k_qk(
    const short* __restrict__ qh, const short* __restrict__ qm, const short* __restrict__ ql,
    const short* __restrict__ kh, const short* __restrict__ km, const short* __restrict__ kl,
    float* __restrict__ pattern, float* __restrict__ mws, float* __restrict__ lws)
{
    const int qt = blockIdx.x, bh = blockIdx.y;
    const int tid = threadIdx.x, w = tid >> 6, lane = tid & 63;
    const int l15 = lane & 15, lhi = lane >> 4;
    const int q0 = qt * 64, rw = q0 + w * 16;

    bf16x8 aqh[2], aqm[2], aql[2];
    const size_t qrow = ((size_t)bh * 2048 + rw + l15) * 64;
    #pragma unroll
    for (int ch = 0; ch < 2; ++ch) {
        aqh[ch] = *(const bf16x8*)&qh[qrow + ch * 32 + lhi * 8];
        aqm[ch] = *(const bf16x8*)&qm[qrow + ch * 32 + lhi * 8];
        aql[ch] = *(const bf16x8*)&ql[qrow + ch * 32 + lhi * 8];
    }

    float m[4], l[4];
    #pragma unroll
    for (int r = 0; r < 4; ++r) { m[r] = -1e30f; l[r] = 0.f; }

    for (int kt = 0; kt <= qt; ++kt) {
        f32x4 acc[4] = {};
        #pragma unroll
        for (int nt = 0; nt < 4; ++nt) {
            const int key = kt * 64 + nt * 16 + l15;
            const size_t krow = ((size_t)bh * 2048 + key) * 64;
            #pragma unroll
            for (int ch = 0; ch < 2; ++ch) {
                bf16x8 bh2 = *(const bf16x8*)&kh[krow + ch * 32 + lhi * 8];
                bf16x8 bm2 = *(const bf16x8*)&km[krow + ch * 32 + lhi * 8];
                bf16x8 bl2 = *(const bf16x8*)&kl[krow + ch * 32 + lhi * 8];
                acc[nt] = MFMA(aqh[ch], bh2, acc[nt]);
                acc[nt] = MFMA(aqh[ch], bm2, acc[nt]);
                acc[nt] = MFMA(aqm[ch], bh2, acc[nt]);
                acc[nt] = MFMA(aqm[ch], bm2, acc[nt]);
                acc[nt] = MFMA(aqh[ch], bl2, acc[nt]);
                acc[nt] = MFMA(aql[ch], bh2, acc[nt]);
            }
        }
        // scale + mask, tile row-max
        float tmax[4] = {-1e30f, -1e30f, -1e30f, -1e30f};
        const bool diag = (kt == qt);
        #pragma unroll
        for (int nt = 0; nt < 4; ++nt) {
            const int key = kt * 64 + nt * 16 + l15;
            #pragma unroll
            for (int r = 0; r < 4; ++r) {
                float s = acc[nt][r] * 0.125f;
                const int row = rw + lhi * 4 + r;
                if (diag && key > row) s = -1e30f;
                acc[nt][r] = s;
                tmax[r] = fmaxf(tmax[r], s);
            }
        }
        // write raw scores
        #pragma unroll
        for (int nt = 0; nt < 4; ++nt) {
            const int key = kt * 64 + nt * 16 + l15;
            const size_t pb = ((size_t)bh * 2048 + rw + lhi * 4) * 2048 + key;
            #pragma unroll
            for (int r = 0; r < 4; ++r)
                pattern[pb + (size_t)r * 2048] = acc[nt][r];
        }
        // reduce max over the 16 lanes sharing the same rows
        #pragma unroll
        for (int off = 1; off < 16; off <<= 1)
            #pragma unroll
            for (int r = 0; r < 4; ++r)
                tmax[r] = fmaxf(tmax[r], __shfl_xor(tmax[r], off));
        // online m,l update
        #pragma unroll
        for (int r = 0; r < 4; ++r) {
            float mn = fmaxf(m[r], tmax[r]);
            l[r] *= __expf(m[r] - mn);
            m[r] = mn;
        }
        float esum[4] = {0.f, 0.f, 0.f, 0.f};
        #pragma unroll
        for (int nt = 0; nt < 4; ++nt)
            #pragma unroll
            for (int r = 0; r < 4; ++r)
                esum[r] += __expf(acc[nt][r] - m[r]);
        #pragma unroll
        for (int off = 1; off < 16; off <<= 1)
            #pragma unroll
            for (int r = 0; r < 4; ++r)
                esum[r] += __shfl_xor(esum[r], off);
        #pragma unroll
        for (int r = 0; r < 4; ++r) l[r] += esum[r];
    }

    if (l15 == 0) {
        #pragma unroll
        for (int r = 0; r < 4; ++r) {
            const int row = rw + lhi * 4 + r;
            mws[bh * 2048 + row] = m[r];
            lws[bh * 2048 + row] = l[r];
        }
    }
}

// ---------------------------------------------------------------------------
// PV: read raw s, p = exp(s-m)/l, write normalized pattern in-place (+ zero
// fill above diagonal), accumulate z = P*V via bf16 MFMA. z stored bf16.
// grid (32 qt, 64 bh), 4 waves.
// ---------------------------------------------------------------------------
__global__ __launch_bounds__(256) void k_pv(
    const short* __restrict__ vT,
    const float* __restrict__ mws, const float* __restrict__ lws,
    float* __restrict__ pattern, short* __restrict__ z)
{
    const int qt = blockIdx.x, bh = blockIdx.y;
    const int b = bh >> 4, h = bh & 15;
    const int tid = threadIdx.x, w = tid >> 6, lane = tid & 63;
    const int l15 = lane & 15, lhi = lane >> 4;
    const int q0 = qt * 64, rw = q0 + w * 16;

    const float mA  = mws[bh * 2048 + rw + l15];
    const float inv = 1.f / lws[bh * 2048 + rw + l15];

    f32x4 acc[4] = {};
    const size_t prow = ((size_t)bh * 2048 + rw + l15) * 2048;
    for (int kt = 0; kt <= qt; ++kt) {
        #pragma unroll
        for (int ch = 0; ch < 2; ++ch) {
            const size_t so = prow + kt * 64 + ch * 32 + lhi * 8;
            float4 s0 = *(const float4*)&pattern[so];
            float4 s1 = *(const float4*)&pattern[so + 4];
            float p0 = __expf(s0.x - mA) * inv;
            float p1 = __expf(s0.y - mA) * inv;
            float p2 = __expf(s0.z - mA) * inv;
            float p3 = __expf(s0.w - mA) * inv;
            float p4 = __expf(s1.x - mA) * inv;
            float p5 = __expf(s1.y - mA) * inv;
            float p6 = __expf(s1.z - mA) * inv;
            float p7 = __expf(s1.w - mA) * inv;
            float4 o0; o0.x = p0; o0.y = p1; o0.z = p2; o0.w = p3;
            float4 o1; o1.x = p4; o1.y = p5; o1.z = p6; o1.w = p7;
            *(float4*)&pattern[so]     = o0;
            *(float4*)&pattern[so + 4] = o1;
            bf16x8 af;
            af[0] = f2bf(p0); af[1] = f2bf(p1); af[2] = f2bf(p2); af[3] = f2bf(p3);
            af[4] = f2bf(p4); af[5] = f2bf(p5); af[6] = f2bf(p6); af[7] = f2bf(p7);
            #pragma unroll
            for (int nt = 0; nt < 4; ++nt) {
                bf16x8 bf = *(const bf16x8*)&vT[((size_t)bh * 64 + nt * 16 + l15) * 2048
                                                + kt * 64 + ch * 32 + lhi * 8];
                acc[nt] = MFMA(af, bf, acc[nt]);
            }
        }
    }
    // store z (bf16, [b][s][h*64+e])
    #pragma unroll
    for (int nt = 0; nt < 4; ++nt) {
        const int e = nt * 16 + l15;
        #pragma unroll
        for (int r = 0; r < 4; ++r) {
            const int row = rw + lhi * 4 + r;
            z[((size_t)(b * 2048 + row)) * 1024 + h * 64 + e] = f2bf(acc[nt][r]);
        }
    }
    // zero-fill strictly-above-diagonal tiles for this block's 64 rows
    float4 z4; z4.x = 0.f; z4.y = 0.f; z4.z = 0.f; z4.w = 0.f;
    for (int kt2 = qt + 1; kt2 < 32; ++kt2) {
        #pragma unroll
        for (int rep = 0; rep < 4; ++rep) {
            int u = tid + rep * 256;               // 0..1023
            int rr = u >> 4, cc = (u & 15) * 4;
            *(float4*)&pattern[((size_t)bh * 2048 + q0 + rr) * 2048 + kt2 * 64 + cc] = z4;
        }
    }
}

// ---------------------------------------------------------------------------
// O projection: out = z * WO + bo, 1-pass bf16 MFMA.
// grid (16 col-tiles, 128 row-tiles), 4 waves.
// ---------------------------------------------------------------------------
__global__ __launch_bounds__(256) void k_oproj(
    const short* __restrict__ z, const short* __restrict__ woT,
    const float* __restrict__ bo, float* __restrict__ out)
{
    const int ct = blockIdx.x, mt = blockIdx.y;
    const int tid = threadIdx.x, w = tid >> 6, lane = tid & 63;
    const int l15 = lane & 15, lhi = lane >> 4;
    const int rw = mt * 64 + w * 16, c0 = ct * 64;

    f32x4 acc[4] = {};
    const size_t zrow = (size_t)(rw + l15) * 1024;
    for (int ch = 0; ch < 32; ++ch) {
        const int d0 = ch * 32 + lhi * 8;
        bf16x8 a = *(const bf16x8*)&z[zrow + d0];
        #pragma unroll
        for (int nt = 0; nt < 4; ++nt) {
            bf16x8 bb = *(const bf16x8*)&woT[(size_t)(c0 + nt * 16 + l15) * 1024 + d0];
            acc[nt] = MFMA(a, bb, acc[nt]);
        }
    }
    #pragma unroll
    for (int nt = 0; nt < 4; ++nt) {
        const int col = c0 + nt * 16 + l15;
        const float bb = bo[col];
        #pragma unroll
        for (int r = 0; r < 4; ++r) {
            const int row = rw + lhi * 4 + r;
            out[(size_t)row * 1024 + col] = acc[nt][r] + bb;
        }
    }
}

// ---------------------------------------------------------------------------
extern "C" void kernel_launch(void* const* d_in, const int* in_sizes, int n_in,
                              void* d_out, int out_size, void* d_ws, size_t ws_size,
                              hipStream_t stream) {
    const float* x  = (const float*)d_in[0];
    const float* Wq = (const float*)d_in[1];
    const float* bq = (const float*)d_in[2];
    const float* Wk = (const float*)d_in[3];
    const float* bk = (const float*)d_in[4];
    const float* Wv = (const float*)d_in[5];
    const float* bv = (const float*)d_in[6];
    const float* Wo = (const float*)d_in[7];
    const float* bo = (const float*)d_in[8];

    float* out      = (float*)d_out;
    float* attn_out = out;
    float* pattern  = out + (size_t)8192 * 1024;

    char* wsb = (char*)d_ws;
    const size_t MiB16 = 16777216, MiB2 = 2097152;
    // q,k 3-split + vT: 7 x 16 MiB
    short* qh3 = (short*)(wsb + 0 * MiB16);
    short* qm3 = (short*)(wsb + 1 * MiB16);
    short* ql3 = (short*)(wsb + 2 * MiB16);
    short* kh3 = (short*)(wsb + 3 * MiB16);
    short* km3 = (short*)(wsb + 4 * MiB16);
    short* kl3 = (short*)(wsb + 5 * MiB16);
    short* vT  = (short*)(wsb + 6 * MiB16);
    // W buffers at 112 MiB: 9 x 2 MiB (QKV 3-split) + woT 2 MiB = 132 MiB total
    char* wb = wsb + 7 * MiB16;
    short* wqh = (short*)(wb + 0 * MiB2);
    short* wqm = (short*)(wb + 1 * MiB2);
    short* wql = (short*)(wb + 2 * MiB2);
    short* wkh = (short*)(wb + 3 * MiB2);
    short* wkm = (short*)(wb + 4 * MiB2);
    short* wkl = (short*)(wb + 5 * MiB2);
    short* wvh = (short*)(wb + 6 * MiB2);
    short* wvm = (short*)(wb + 7 * MiB2);
    short* wvl = (short*)(wb + 8 * MiB2);
    short* woT = (short*)(wb + 9 * MiB2);
    // aliases (dead-after-use regions):
    short* zbuf = qh3;                    // z written by k_pv, after k_qk's last read of qh3
    float* mws  = (float*)(wb + 0 * MiB2);          // alias wq hi (dead after k_proj)
    float* lws  = (float*)(wb + 0 * MiB2 + 524288); // alias wq hi upper half

    k_conv_w <<<12288, 256, 0, stream>>>(Wq, Wk, Wv,
                                         wqh, wqm, wql, wkh, wkm, wkl, wvh, wvm, wvl);
    k_conv_wo<<<4096, 256, 0, stream>>>(Wo, woT);
    k_proj   <<<dim3(48, 128), 256, 0, stream>>>(x,
                                         wqh, wqm, wql, wkh, wkm, wkl, wvh, wvm, wvl,
                                         bq, bk, bv,
                                         qh3, qm3, ql3, kh3, km3, kl3, vT);
    k_qk     <<<dim3(32, 64), 256, 0, stream>>>(qh3, qm3, ql3, kh3, km3, kl3,
                                         pattern, mws, lws);
    k_pv     <<<dim3(32, 64), 256, 0, stream>>>(vT, mws, lws, pattern, zbuf);
    k_oproj  <<<dim3(16, 128), 256, 0, stream>>>(zbuf, woT, bo, attn_out);
}

// Round 3
// 1807.280 us; speedup vs baseline: 1.6310x; 1.6310x over previous
//
#include <hip/hip_runtime.h>
#include <hip/hip_bf16.h>

// B=4, S=2048, D_MODEL=1024, H=16, E=64, M=8192 rows, bh = b*16+h (64)
// Precision: fp32 value = hi + lo (2x fp16, ~24 mantissa bits total, fp32-exact).
// Products via 3 MFMA passes (hh, hl, lh); ll ~ 2^-24 rel -> dropped.
// MFMA shape: mfma_f32_16x16x32_f16.
//   A-frag: lane l holds A[m=l&15][k=(l>>4)*8+j]  (16B contiguous)
//   B-frag: lane l holds B[k=(l>>4)*8+j][n=l&15]  (read from [n][k]-major array)
//   C/D  : lane l holds D[row=(l>>4)*4+r][col=l&15]

typedef _Float16 half_t;
typedef __attribute__((ext_vector_type(8))) _Float16 f16x8;
typedef __attribute__((ext_vector_type(4))) float f32x4;

#define MFMA16(a, b, c) __builtin_amdgcn_mfma_f32_16x16x32_f16(a, b, c, 0, 0, 0)

__device__ __forceinline__ void split2(float v, half_t& h, half_t& l) {
    h = (half_t)v;
    l = (half_t)(v - (float)h);
}

// ---------------------------------------------------------------------------
// x [8192][1024] fp32 -> xh, xl fp16 planes
// ---------------------------------------------------------------------------
__global__ __launch_bounds__(256) void k_conv_x(
    const float* __restrict__ x, half_t* __restrict__ xh, half_t* __restrict__ xl)
{
    const size_t i = ((size_t)blockIdx.x * 256 + threadIdx.x) * 8;
    float4 a = *(const float4*)&x[i];
    float4 b = *(const float4*)&x[i + 4];
    float v[8] = {a.x, a.y, a.z, a.w, b.x, b.y, b.z, b.w};
    f16x8 H, L;
    #pragma unroll
    for (int j = 0; j < 8; ++j) {
        half_t hh, hl; split2(v[j], hh, hl);
        H[j] = hh; L[j] = hl;
    }
    *(f16x8*)&xh[i] = H;
    *(f16x8*)&xl[i] = L;
}

// ---------------------------------------------------------------------------
// W_{Q,K,V} [16][1024 d][64 e] fp32 -> wh, wl fp16 [n=3072][k=1024] (transposed)
// n = mat*1024 + h*64 + e.  LDS-transpose per 64x64 tile.
// grid: 768 = mat(3) * h(16) * dt(16)
// ---------------------------------------------------------------------------
__global__ __launch_bounds__(256) void k_conv_w(
    const float* __restrict__ Wq, const float* __restrict__ Wk, const float* __restrict__ Wv,
    half_t* __restrict__ wh, half_t* __restrict__ wl)
{
    const int bid = blockIdx.x;
    const int mat = bid >> 8, h = (bid >> 4) & 15, dt = bid & 15;
    const float* W = (mat == 0) ? Wq : (mat == 1) ? Wk : Wv;
    __shared__ float t[64][65];
    const int tid = threadIdx.x;
    #pragma unroll
    for (int rep = 0; rep < 4; ++rep) {
        int idx = tid + rep * 256;
        int r = idx >> 4, c4 = (idx & 15) * 4;       // d-row r, e-cols
        float4 v4 = *(const float4*)&W[(size_t)h * 65536 + (size_t)(dt * 64 + r) * 64 + c4];
        t[r][c4 + 0] = v4.x; t[r][c4 + 1] = v4.y;
        t[r][c4 + 2] = v4.z; t[r][c4 + 3] = v4.w;
    }
    __syncthreads();
    #pragma unroll
    for (int rep = 0; rep < 4; ++rep) {
        int idx = tid + rep * 256;
        int e = idx >> 4, g = (idx & 15) * 4;        // e-row, d-chunk
        size_t o = ((size_t)(mat * 1024 + h * 64 + e)) * 1024 + dt * 64 + g;
        #pragma unroll
        for (int j = 0; j < 4; ++j) {
            half_t hh, hl; split2(t[g + j][e], hh, hl);
            wh[o + j] = hh; wl[o + j] = hl;
        }
    }
}

// W_O [1024 hd][1024 dm] fp32 -> woT fp16 [dm][hd]
__global__ __launch_bounds__(256) void k_conv_wo(
    const float* __restrict__ Wo, half_t* __restrict__ woT)
{
    const int bi = blockIdx.x >> 4, bj = blockIdx.x & 15;
    __shared__ float t[64][65];
    const int tid = threadIdx.x;
    #pragma unroll
    for (int rep = 0; rep < 4; ++rep) {
        int idx = tid + rep * 256;
        int r = idx >> 4, c4 = (idx & 15) * 4;
        float4 v4 = *(const float4*)&Wo[(size_t)(bi * 64 + r) * 1024 + bj * 64 + c4];
        t[r][c4 + 0] = v4.x; t[r][c4 + 1] = v4.y;
        t[r][c4 + 2] = v4.z; t[r][c4 + 3] = v4.w;
    }
    __syncthreads();
    #pragma unroll
    for (int rep = 0; rep < 4; ++rep) {
        int idx = tid + rep * 256;
        int dm = idx >> 4, g = (idx & 15) * 4;
        size_t o = (size_t)(bj * 64 + dm) * 1024 + bi * 64 + g;
        #pragma unroll
        for (int j = 0; j < 4; ++j)
            woT[o + j] = (half_t)t[g + j][dm];
    }
}

// ---------------------------------------------------------------------------
// QKV projection GEMM: M=8192, N=3072, K=1024, 3-pass fp16-split MFMA.
// 128x128 tile, BK=32, double-buffered reg-staged LDS, XOR-swizzled.
// grid (24 n-tiles, 64 m-tiles), 256 thr = 4 waves (2x2), wave = 64x64.
// ---------------------------------------------------------------------------
__global__ __launch_bounds__(256) void k_proj(
    const half_t* __restrict__ xh, const half_t* __restrict__ xl,
    const half_t* __restrict__ wh, const half_t* __restrict__ wl,
    const float* __restrict__ bq, const float* __restrict__ bk, const float* __restrict__ bv,
    half_t* __restrict__ oqh, half_t* __restrict__ oql,
    half_t* __restrict__ okh, half_t* __restrict__ okl,
    half_t* __restrict__ ovT)
{
    __shared__ half_t lds[2][4][128 * 32];   // [buf][Ah,Al,Bh,Bl][row*32 + k]
    const int tid = threadIdx.x, w = tid >> 6, lane = tid & 63;
    const int l15 = lane & 15, lhi = lane >> 4;
    const int wm = w >> 1, wn = w & 1;
    const int m0 = blockIdx.y * 128, n0 = blockIdx.x * 128;

    // staging: wave w covers rows w*32 .. w*32+32 of each plane
    const int r0 = w * 32 + (lane >> 2);
    const int r1 = r0 + 16;
    const int u  = lane & 3;                 // 16B slot within 64B row
    const size_t gA0 = (size_t)(m0 + r0) * 1024 + u * 8;
    const size_t gA1 = (size_t)(m0 + r1) * 1024 + u * 8;
    const size_t gB0 = (size_t)(n0 + r0) * 1024 + u * 8;
    const size_t gB1 = (size_t)(n0 + r1) * 1024 + u * 8;
    const int d0 = r0 * 32 + ((u ^ ((r0 >> 1) & 3)) * 8);   // swizzled phys slot
    const int d1 = r1 * 32 + ((u ^ ((r1 >> 1) & 3)) * 8);

    int4 st[8];
    auto LOAD = [&](int kb) {
        st[0] = *(const int4*)&xh[gA0 + kb];
        st[1] = *(const int4*)&xh[gA1 + kb];
        st[2] = *(const int4*)&xl[gA0 + kb];
        st[3] = *(const int4*)&xl[gA1 + kb];
        st[4] = *(const int4*)&wh[gB0 + kb];
        st[5] = *(const int4*)&wh[gB1 + kb];
        st[6] = *(const int4*)&wl[gB0 + kb];
        st[7] = *(const int4*)&wl[gB1 + kb];
    };
    auto WRITE = [&](int bf) {
        *(int4*)&lds[bf][0][d0] = st[0];
        *(int4*)&lds[bf][0][d1] = st[1];
        *(int4*)&lds[bf][1][d0] = st[2];
        *(int4*)&lds[bf][1][d1] = st[3];
        *(int4*)&lds[bf][2][d0] = st[4];
        *(int4*)&lds[bf][2][d1] = st[5];
        *(int4*)&lds[bf][3][d0] = st[6];
        *(int4*)&lds[bf][3][d1] = st[7];
    };

    f32x4 acc[4][4] = {};

    LOAD(0); WRITE(0); __syncthreads();
    int cur = 0;
    for (int ks = 0; ks < 32; ++ks) {
        if (ks < 31) LOAD((ks + 1) * 32);
        f16x8 fah[4], fal[4], fbh[4], fbl[4];
        #pragma unroll
        for (int i = 0; i < 4; ++i) {
            const int ra = wm * 64 + i * 16 + l15;
            const int aa = ra * 32 + ((lhi ^ ((ra >> 1) & 3)) * 8);
            fah[i] = *(const f16x8*)&lds[cur][0][aa];
            fal[i] = *(const f16x8*)&lds[cur][1][aa];
            const int rb = wn * 64 + i * 16 + l15;
            const int ab = rb * 32 + ((lhi ^ ((rb >> 1) & 3)) * 8);
            fbh[i] = *(const f16x8*)&lds[cur][2][ab];
            fbl[i] = *(const f16x8*)&lds[cur][3][ab];
        }
        #pragma unroll
        for (int mi = 0; mi < 4; ++mi)
            #pragma unroll
            for (int ni = 0; ni < 4; ++ni) {
                acc[mi][ni] = MFMA16(fah[mi], fbh[ni], acc[mi][ni]);
                acc[mi][ni] = MFMA16(fah[mi], fbl[ni], acc[mi][ni]);
                acc[mi][ni] = MFMA16(fal[mi], fbh[ni], acc[mi][ni]);
            }
        if (ks < 31) WRITE(cur ^ 1);
        __syncthreads();
        cur ^= 1;
    }

    #pragma unroll
    for (int ni = 0; ni < 4; ++ni) {
        const int n = n0 + wn * 64 + ni * 16 + l15;
        const int mat = n >> 10, nn = n & 1023;
        const int h = nn >> 6, e = nn & 63;
        const float bias = (mat == 0 ? bq : mat == 1 ? bk : bv)[h * 64 + e];
        #pragma unroll
        for (int mi = 0; mi < 4; ++mi)
            #pragma unroll
            for (int r = 0; r < 4; ++r) {
                const int m = m0 + wm * 64 + mi * 16 + lhi * 4 + r;
                const int b = m >> 11, s = m & 2047;
                const int bh_i = b * 16 + h;
                const float v = acc[mi][ni][r] + bias;
                if (mat == 2) {
                    ovT[((size_t)bh_i * 64 + e) * 2048 + s] = (half_t)v;
                } else {
                    half_t hh, hl; split2(v, hh, hl);
                    const size_t o = ((size_t)bh_i * 2048 + s) * 64 + e;
                    if (mat == 0) { oqh[o] = hh; oql[o] = hl; }
                    else          { okh[o] = hh; okl[o] = hl; }
                }
            }
    }
}

// ---------------------------------------------------------------------------
// QK^T (3-pass fp16-split) + causal mask; raw fp32 scores -> pattern buffer;
// online per-row (m, l).  grid (32 qt, 64 bh), 4 waves x 16 q-rows.
// K-tiles LDS-staged (shared by all waves), double-buffered, swizzled.
// ---------------------------------------------------------------------------
__global__ __launch_bounds__(256) void k_qk(
    const half_t* __restrict__ qh, const half_t* __restrict__ ql,
    const half_t* __restrict__ kh, const half_t* __restrict__ kl,
    float* __restrict__ pattern, float* __restrict__ mws, float* __restrict__ lws)
{
    __shared__ half_t lds[2][2][64 * 64];    // [buf][Kh,Kl][key*64 + e]
    const int qt = 31 - blockIdx.x, bh = blockIdx.y;
    const int tid = threadIdx.x, w = tid >> 6, lane = tid & 63;
    const int l15 = lane & 15, lhi = lane >> 4;
    const int rw = qt * 64 + w * 16;

    // q fragments
    const size_t qrow = ((size_t)bh * 2048 + rw + l15) * 64;
    f16x8 aqh[2], aql[2];
    #pragma unroll
    for (int ch = 0; ch < 2; ++ch) {
        aqh[ch] = *(const f16x8*)&qh[qrow + ch * 32 + lhi * 8];
        aql[ch] = *(const f16x8*)&ql[qrow + ch * 32 + lhi * 8];
    }

    // staging: wave w covers key-rows w*16 .. +16; 8 slots of 16B per 128B row
    const int sr0 = w * 16 + (lane >> 3);
    const int sr1 = sr0 + 8;
    const int su  = lane & 7;
    const size_t kbase = (size_t)bh * 2048 * 64;
    const int sd0 = sr0 * 64 + ((su ^ (sr0 & 7)) * 8);
    const int sd1 = sr1 * 64 + ((su ^ (sr1 & 7)) * 8);

    int4 st[4];
    auto LOADK = [&](int kt) {
        const size_t g0 = kbase + (size_t)(kt * 64 + sr0) * 64 + su * 8;
        const size_t g1 = kbase + (size_t)(kt * 64 + sr1) * 64 + su * 8;
        st[0] = *(const int4*)&kh[g0];
        st[1] = *(const int4*)&kh[g1];
        st[2] = *(const int4*)&kl[g0];
        st[3] = *(const int4*)&kl[g1];
    };
    auto WRITEK = [&](int bf) {
        *(int4*)&lds[bf][0][sd0] = st[0];
        *(int4*)&lds[bf][0][sd1] = st[1];
        *(int4*)&lds[bf][1][sd0] = st[2];
        *(int4*)&lds[bf][1][sd1] = st[3];
    };

    float m[4], l[4];
    #pragma unroll
    for (int r = 0; r < 4; ++r) { m[r] = -1e30f; l[r] = 0.f; }

    LOADK(0); WRITEK(0); __syncthreads();
    int cur = 0;
    for (int kt = 0; kt <= qt; ++kt) {
        if (kt < qt) LOADK(kt + 1);
        f32x4 acc[4] = {};
        #pragma unroll
        for (int nt = 0; nt < 4; ++nt) {
            const int kr = nt * 16 + l15;
            #pragma unroll
            for (int ch = 0; ch < 2; ++ch) {
                const int slot = ch * 4 + lhi;
                const int ad = kr * 64 + ((slot ^ (kr & 7)) * 8);
                f16x8 bh8 = *(const f16x8*)&lds[cur][0][ad];
                f16x8 bl8 = *(const f16x8*)&lds[cur][1][ad];
                acc[nt] = MFMA16(aqh[ch], bh8, acc[nt]);
                acc[nt] = MFMA16(aqh[ch], bl8, acc[nt]);
                acc[nt] = MFMA16(aql[ch], bh8, acc[nt]);
            }
        }
        // scale + causal mask + tile row-max
        float tmax[4] = {-1e30f, -1e30f, -1e30f, -1e30f};
        const bool diag = (kt == qt);
        #pragma unroll
        for (int nt = 0; nt < 4; ++nt) {
            const int key = kt * 64 + nt * 16 + l15;
            #pragma unroll
            for (int r = 0; r < 4; ++r) {
                float s = acc[nt][r] * 0.125f;
                const int row = rw + lhi * 4 + r;
                if (diag && key > row) s = -1e30f;
                acc[nt][r] = s;
                tmax[r] = fmaxf(tmax[r], s);
            }
        }
        // write raw scores
        #pragma unroll
        for (int nt = 0; nt < 4; ++nt) {
            const int key = kt * 64 + nt * 16 + l15;
            const size_t pb = ((size_t)bh * 2048 + rw + lhi * 4) * 2048 + key;
            #pragma unroll
            for (int r = 0; r < 4; ++r)
                pattern[pb + (size_t)r * 2048] = acc[nt][r];
        }
        // reduce max over the 16 lanes sharing rows
        #pragma unroll
        for (int off = 1; off < 16; off <<= 1)
            #pragma unroll
            for (int r = 0; r < 4; ++r)
                tmax[r] = fmaxf(tmax[r], __shfl_xor(tmax[r], off));
        #pragma unroll
        for (int r = 0; r < 4; ++r) {
            const float mn = fmaxf(m[r], tmax[r]);
            l[r] *= __expf(m[r] - mn);
            m[r] = mn;
        }
        float esum[4] = {0.f, 0.f, 0.f, 0.f};
        #pragma unroll
        for (int nt = 0; nt < 4; ++nt)
            #pragma unroll
            for (int r = 0; r < 4; ++r)
                esum[r] += __expf(acc[nt][r] - m[r]);
        #pragma unroll
        for (int off = 1; off < 16; off <<= 1)
            #pragma unroll
            for (int r = 0; r < 4; ++r)
                esum[r] += __shfl_xor(esum[r], off);
        #pragma unroll
        for (int r = 0; r < 4; ++r) l[r] += esum[r];

        if (kt < qt) WRITEK(cur ^ 1);
        __syncthreads();
        cur ^= 1;
    }

    if (l15 == 0) {
        #pragma unroll
        for (int r = 0; r < 4; ++r) {
            const int row = rw + lhi * 4 + r;
            mws[bh * 2048 + row] = m[r];
            lws[bh * 2048 + row] = l[r];
        }
    }
}

// ---------------------------------------------------------------------------
// PV: p = exp(s-m)/l, write normalized pattern in-place (+ zero upper),
// z = P*V via fp16 MFMA.  grid (32 qt, 64 bh).
// ---------------------------------------------------------------------------
__global__ __launch_bounds__(256) void k_pv(
    const half_t* __restrict__ vT,
    const float* __restrict__ mws, const float* __restrict__ lws,
    float* __restrict__ pattern, half_t* __restrict__ z)
{
    const int qt = 31 - blockIdx.x, bh = blockIdx.y;
    const int b = bh >> 4, h = bh & 15;
    const int tid = threadIdx.x, w = tid >> 6, lane = tid & 63;
    const int l15 = lane & 15, lhi = lane >> 4;
    const int q0 = qt * 64, rw = q0 + w * 16;

    const float mA  = mws[bh * 2048 + rw + l15];
    const float inv = 1.f / lws[bh * 2048 + rw + l15];

    f32x4 acc[4] = {};
    const size_t prow = ((size_t)bh * 2048 + rw + l15) * 2048;
    for (int kt = 0; kt <= qt; ++kt) {
        #pragma unroll
        for (int ch = 0; ch < 2; ++ch) {
            const size_t so = prow + kt * 64 + ch * 32 + lhi * 8;
            float4 s0 = *(const float4*)&pattern[so];
            float4 s1 = *(const float4*)&pattern[so + 4];
            const float p0 = __expf(s0.x - mA) * inv;
            const float p1 = __expf(s0.y - mA) * inv;
            const float p2 = __expf(s0.z - mA) * inv;
            const float p3 = __expf(s0.w - mA) * inv;
            const float p4 = __expf(s1.x - mA) * inv;
            const float p5 = __expf(s1.y - mA) * inv;
            const float p6 = __expf(s1.z - mA) * inv;
            const float p7 = __expf(s1.w - mA) * inv;
            float4 o0; o0.x = p0; o0.y = p1; o0.z = p2; o0.w = p3;
            float4 o1; o1.x = p4; o1.y = p5; o1.z = p6; o1.w = p7;
            *(float4*)&pattern[so]     = o0;
            *(float4*)&pattern[so + 4] = o1;
            f16x8 af;
            af[0] = (half_t)p0; af[1] = (half_t)p1; af[2] = (half_t)p2; af[3] = (half_t)p3;
            af[4] = (half_t)p4; af[5] = (half_t)p5; af[6] = (half_t)p6; af[7] = (half_t)p7;
            #pragma unroll
            for (int nt = 0; nt < 4; ++nt) {
                f16x8 bf8 = *(const f16x8*)&vT[((size_t)bh * 64 + nt * 16 + l15) * 2048
                                               + kt * 64 + ch * 32 + lhi * 8];
                acc[nt] = MFMA16(af, bf8, acc[nt]);
            }
        }
    }
    #pragma unroll
    for (int nt = 0; nt < 4; ++nt) {
        const int e = nt * 16 + l15;
        #pragma unroll
        for (int r = 0; r < 4; ++r) {
            const int row = rw + lhi * 4 + r;
            z[((size_t)(b * 2048 + row)) * 1024 + h * 64 + e] = (half_t)acc[nt][r];
        }
    }
    // zero-fill strictly-above-diagonal tiles
    float4 z4; z4.x = 0.f; z4.y = 0.f; z4.z = 0.f; z4.w = 0.f;
    for (int kt2 = qt + 1; kt2 < 32; ++kt2) {
        #pragma unroll
        for (int rep = 0; rep < 4; ++rep) {
            int uu = tid + rep * 256;
            int rr = uu >> 4, cc = (uu & 15) * 4;
            *(float4*)&pattern[((size_t)bh * 2048 + q0 + rr) * 2048 + kt2 * 64 + cc] = z4;
        }
    }
}

// ---------------------------------------------------------------------------
// O projection GEMM: M=8192, N=1024, K=1024, 1-pass fp16 MFMA.
// Same skeleton as k_proj, 1 plane each.  grid (8, 64).
// ---------------------------------------------------------------------------
__global__ __launch_bounds__(256) void k_oproj(
    const half_t* __restrict__ z, const half_t* __restrict__ woT,
    const float* __restrict__ bo, float* __restrict__ out)
{
    __shared__ half_t lds[2][2][128 * 32];
    const int tid = threadIdx.x, w = tid >> 6, lane = tid & 63;
    const int l15 = lane & 15, lhi = lane >> 4;
    const int wm = w >> 1, wn = w & 1;
    const int m0 = blockIdx.y * 128, n0 = blockIdx.x * 128;

    const int r0 = w * 32 + (lane >> 2);
    const int r1 = r0 + 16;
    const int u  = lane & 3;
    const size_t gA0 = (size_t)(m0 + r0) * 1024 + u * 8;
    const size_t gA1 = (size_t)(m0 + r1) * 1024 + u * 8;
    const size_t gB0 = (size_t)(n0 + r0) * 1024 + u * 8;
    const size_t gB1 = (size_t)(n0 + r1) * 1024 + u * 8;
    const int d0 = r0 * 32 + ((u ^ ((r0 >> 1) & 3)) * 8);
    const int d1 = r1 * 32 + ((u ^ ((r1 >> 1) & 3)) * 8);

    int4 st[4];
    auto LOAD = [&](int kb) {
        st[0] = *(const int4*)&z[gA0 + kb];
        st[1] = *(const int4*)&z[gA1 + kb];
        st[2] = *(const int4*)&woT[gB0 + kb];
        st[3] = *(const int4*)&woT[gB1 + kb];
    };
    auto WRITE = [&](int bf) {
        *(int4*)&lds[bf][0][d0] = st[0];
        *(int4*)&lds[bf][0][d1] = st[1];
        *(int4*)&lds[bf][1][d0] = st[2];
        *(int4*)&lds[bf][1][d1] = st[3];
    };

    f32x4 acc[4][4] = {};
    LOAD(0); WRITE(0); __syncthreads();
    int cur = 0;
    for (int ks = 0; ks < 32; ++ks) {
        if (ks < 31) LOAD((ks + 1) * 32);
        f16x8 fa[4], fb[4];
        #pragma unroll
        for (int i = 0; i < 4; ++i) {
            const int ra = wm * 64 + i * 16 + l15;
            fa[i] = *(const f16x8*)&lds[cur][0][ra * 32 + ((lhi ^ ((ra >> 1) & 3)) * 8)];
            const int rb = wn * 64 + i * 16 + l15;
            fb[i] = *(const f16x8*)&lds[cur][1][rb * 32 + ((lhi ^ ((rb >> 1) & 3)) * 8)];
        }
        #pragma unroll
        for (int mi = 0; mi < 4; ++mi)
            #pragma unroll
            for (int ni = 0; ni < 4; ++ni)
                acc[mi][ni] = MFMA16(fa[mi], fb[ni], acc[mi][ni]);
        if (ks < 31) WRITE(cur ^ 1);
        __syncthreads();
        cur ^= 1;
    }

    #pragma unroll
    for (int ni = 0; ni < 4; ++ni) {
        const int n = n0 + wn * 64 + ni * 16 + l15;
        const float bb = bo[n];
        #pragma unroll
        for (int mi = 0; mi < 4; ++mi)
            #pragma unroll
            for (int r = 0; r < 4; ++r) {
                const int m = m0 + wm * 64 + mi * 16 + lhi * 4 + r;
                out[(size_t)m * 1024 + n] = acc[mi][ni][r] + bb;
            }
    }
}

// ---------------------------------------------------------------------------
extern "C" void kernel_launch(void* const* d_in, const int* in_sizes, int n_in,
                              void* d_out, int out_size, void* d_ws, size_t ws_size,
                              hipStream_t stream) {
    const float* x  = (const float*)d_in[0];
    const float* Wq = (const float*)d_in[1];
    const float* bq = (const float*)d_in[2];
    const float* Wk = (const float*)d_in[3];
    const float* bk = (const float*)d_in[4];
    const float* Wv = (const float*)d_in[5];
    const float* bv = (const float*)d_in[6];
    const float* Wo = (const float*)d_in[7];
    const float* bo = (const float*)d_in[8];

    float* out      = (float*)d_out;
    float* attn_out = out;
    float* pattern  = out + (size_t)8192 * 1024;

    char* wsb = (char*)d_ws;
    const size_t M16 = 16777216;
    half_t* qh  = (half_t*)(wsb + 0 * M16);
    half_t* ql  = (half_t*)(wsb + 1 * M16);
    half_t* kh  = (half_t*)(wsb + 2 * M16);
    half_t* kl  = (half_t*)(wsb + 3 * M16);
    half_t* vT  = (half_t*)(wsb + 4 * M16);
    half_t* xh  = (half_t*)(wsb + 5 * M16);
    half_t* xl  = (half_t*)(wsb + 6 * M16);
    half_t* wh  = (half_t*)(wsb + 7 * M16);                 // 6 MiB
    half_t* wl  = (half_t*)(wsb + 7 * M16 + 6291456);       // 6 MiB
    half_t* woT = (half_t*)(wsb + 7 * M16 + 12582912);      // 2 MiB
    // aliases of regions dead after k_proj:
    half_t* zbuf = xh;                                      // z (fp16, 16 MiB)
    float*  mws  = (float*)xl;                              // 512 KiB
    float*  lws  = (float*)(wsb + 6 * M16 + 524288);        // 512 KiB

    k_conv_x <<<4096, 256, 0, stream>>>(x, xh, xl);
    k_conv_w <<<768,  256, 0, stream>>>(Wq, Wk, Wv, wh, wl);
    k_conv_wo<<<256,  256, 0, stream>>>(Wo, woT);
    k_proj   <<<dim3(24, 64), 256, 0, stream>>>(xh, xl, wh, wl, bq, bk, bv,
                                                qh, ql, kh, kl, vT);
    k_qk     <<<dim3(32, 64), 256, 0, stream>>>(qh, ql, kh, kl, pattern, mws, lws);
    k_pv     <<<dim3(32, 64), 256, 0, stream>>>(vT, mws, lws, pattern, zbuf);
    k_oproj  <<<dim3(8, 64),  256, 0, stream>>>(zbuf, woT, bo, attn_out);
}

// Round 4
// 1543.885 us; speedup vs baseline: 1.9093x; 1.1706x over previous
//
#include <hip/hip_runtime.h>
#include <hip/hip_bf16.h>

// B=4, S=2048, D_MODEL=1024, H=16, E=64, M=8192 rows, bh = b*16+h (64)
// Precision: fp32 value = hi + lo (2x fp16, ~24 mantissa bits total, fp32-exact).
// Products via 3 MFMA passes (hh, hl, lh); ll ~ 2^-24 rel -> dropped.
// MFMA shape: mfma_f32_16x16x32_f16.
//   A-frag: lane l holds A[m=l&15][k=(l>>4)*8+j]  (16B contiguous)
//   B-frag: lane l holds B[k=(l>>4)*8+j][n=l&15]  (read from [n][k]-major array)
//   C/D  : lane l holds D[row=(l>>4)*4+r][col=l&15]

typedef _Float16 half_t;
typedef __attribute__((ext_vector_type(8))) _Float16 f16x8;
typedef __attribute__((ext_vector_type(4))) _Float16 f16x4;
typedef __attribute__((ext_vector_type(4))) float f32x4;

#define MFMA16(a, b, c) __builtin_amdgcn_mfma_f32_16x16x32_f16(a, b, c, 0, 0, 0)

__device__ __forceinline__ void split2(float v, half_t& h, half_t& l) {
    h = (half_t)v;
    l = (half_t)(v - (float)h);
}

// ---------------------------------------------------------------------------
// x [8192][1024] fp32 -> xh, xl fp16 planes
// ---------------------------------------------------------------------------
__global__ __launch_bounds__(256) void k_conv_x(
    const float* __restrict__ x, half_t* __restrict__ xh, half_t* __restrict__ xl)
{
    const size_t i = ((size_t)blockIdx.x * 256 + threadIdx.x) * 8;
    float4 a = *(const float4*)&x[i];
    float4 b = *(const float4*)&x[i + 4];
    float v[8] = {a.x, a.y, a.z, a.w, b.x, b.y, b.z, b.w};
    f16x8 H, L;
    #pragma unroll
    for (int j = 0; j < 8; ++j) {
        half_t hh, hl; split2(v[j], hh, hl);
        H[j] = hh; L[j] = hl;
    }
    *(f16x8*)&xh[i] = H;
    *(f16x8*)&xl[i] = L;
}

// ---------------------------------------------------------------------------
// W_{Q,K,V} [16][1024 d][64 e] fp32 -> wh, wl fp16 [n=3072][k=1024] (transposed)
// ---------------------------------------------------------------------------
__global__ __launch_bounds__(256) void k_conv_w(
    const float* __restrict__ Wq, const float* __restrict__ Wk, const float* __restrict__ Wv,
    half_t* __restrict__ wh, half_t* __restrict__ wl)
{
    const int bid = blockIdx.x;
    const int mat = bid >> 8, h = (bid >> 4) & 15, dt = bid & 15;
    const float* W = (mat == 0) ? Wq : (mat == 1) ? Wk : Wv;
    __shared__ float t[64][65];
    const int tid = threadIdx.x;
    #pragma unroll
    for (int rep = 0; rep < 4; ++rep) {
        int idx = tid + rep * 256;
        int r = idx >> 4, c4 = (idx & 15) * 4;
        float4 v4 = *(const float4*)&W[(size_t)h * 65536 + (size_t)(dt * 64 + r) * 64 + c4];
        t[r][c4 + 0] = v4.x; t[r][c4 + 1] = v4.y;
        t[r][c4 + 2] = v4.z; t[r][c4 + 3] = v4.w;
    }
    __syncthreads();
    #pragma unroll
    for (int rep = 0; rep < 4; ++rep) {
        int idx = tid + rep * 256;
        int e = idx >> 4, g = (idx & 15) * 4;
        size_t o = ((size_t)(mat * 1024 + h * 64 + e)) * 1024 + dt * 64 + g;
        #pragma unroll
        for (int j = 0; j < 4; ++j) {
            half_t hh, hl; split2(t[g + j][e], hh, hl);
            wh[o + j] = hh; wl[o + j] = hl;
        }
    }
}

// W_O [1024 hd][1024 dm] fp32 -> woT fp16 [dm][hd]
__global__ __launch_bounds__(256) void k_conv_wo(
    const float* __restrict__ Wo, half_t* __restrict__ woT)
{
    const int bi = blockIdx.x >> 4, bj = blockIdx.x & 15;
    __shared__ float t[64][65];
    const int tid = threadIdx.x;
    #pragma unroll
    for (int rep = 0; rep < 4; ++rep) {
        int idx = tid + rep * 256;
        int r = idx >> 4, c4 = (idx & 15) * 4;
        float4 v4 = *(const float4*)&Wo[(size_t)(bi * 64 + r) * 1024 + bj * 64 + c4];
        t[r][c4 + 0] = v4.x; t[r][c4 + 1] = v4.y;
        t[r][c4 + 2] = v4.z; t[r][c4 + 3] = v4.w;
    }
    __syncthreads();
    #pragma unroll
    for (int rep = 0; rep < 4; ++rep) {
        int idx = tid + rep * 256;
        int dm = idx >> 4, g = (idx & 15) * 4;
        size_t o = (size_t)(bj * 64 + dm) * 1024 + bi * 64 + g;
        #pragma unroll
        for (int j = 0; j < 4; ++j)
            woT[o + j] = (half_t)t[g + j][dm];
    }
}

// ---------------------------------------------------------------------------
// QKV projection GEMM: M=8192, N=3072, K=1024, 3-pass fp16-split MFMA.
// ---------------------------------------------------------------------------
__global__ __launch_bounds__(256) void k_proj(
    const half_t* __restrict__ xh, const half_t* __restrict__ xl,
    const half_t* __restrict__ wh, const half_t* __restrict__ wl,
    const float* __restrict__ bq, const float* __restrict__ bk, const float* __restrict__ bv,
    half_t* __restrict__ oqh, half_t* __restrict__ oql,
    half_t* __restrict__ okh, half_t* __restrict__ okl,
    half_t* __restrict__ ovT)
{
    __shared__ half_t lds[2][4][128 * 32];
    const int tid = threadIdx.x, w = tid >> 6, lane = tid & 63;
    const int l15 = lane & 15, lhi = lane >> 4;
    const int wm = w >> 1, wn = w & 1;
    const int m0 = blockIdx.y * 128, n0 = blockIdx.x * 128;

    const int r0 = w * 32 + (lane >> 2);
    const int r1 = r0 + 16;
    const int u  = lane & 3;
    const size_t gA0 = (size_t)(m0 + r0) * 1024 + u * 8;
    const size_t gA1 = (size_t)(m0 + r1) * 1024 + u * 8;
    const size_t gB0 = (size_t)(n0 + r0) * 1024 + u * 8;
    const size_t gB1 = (size_t)(n0 + r1) * 1024 + u * 8;
    const int d0 = r0 * 32 + ((u ^ ((r0 >> 1) & 3)) * 8);
    const int d1 = r1 * 32 + ((u ^ ((r1 >> 1) & 3)) * 8);

    int4 st[8];
    auto LOAD = [&](int kb) {
        st[0] = *(const int4*)&xh[gA0 + kb];
        st[1] = *(const int4*)&xh[gA1 + kb];
        st[2] = *(const int4*)&xl[gA0 + kb];
        st[3] = *(const int4*)&xl[gA1 + kb];
        st[4] = *(const int4*)&wh[gB0 + kb];
        st[5] = *(const int4*)&wh[gB1 + kb];
        st[6] = *(const int4*)&wl[gB0 + kb];
        st[7] = *(const int4*)&wl[gB1 + kb];
    };
    auto WRITE = [&](int bf) {
        *(int4*)&lds[bf][0][d0] = st[0];
        *(int4*)&lds[bf][0][d1] = st[1];
        *(int4*)&lds[bf][1][d0] = st[2];
        *(int4*)&lds[bf][1][d1] = st[3];
        *(int4*)&lds[bf][2][d0] = st[4];
        *(int4*)&lds[bf][2][d1] = st[5];
        *(int4*)&lds[bf][3][d0] = st[6];
        *(int4*)&lds[bf][3][d1] = st[7];
    };

    f32x4 acc[4][4] = {};

    LOAD(0); WRITE(0); __syncthreads();
    int cur = 0;
    for (int ks = 0; ks < 32; ++ks) {
        if (ks < 31) LOAD((ks + 1) * 32);
        f16x8 fah[4], fal[4], fbh[4], fbl[4];
        #pragma unroll
        for (int i = 0; i < 4; ++i) {
            const int ra = wm * 64 + i * 16 + l15;
            const int aa = ra * 32 + ((lhi ^ ((ra >> 1) & 3)) * 8);
            fah[i] = *(const f16x8*)&lds[cur][0][aa];
            fal[i] = *(const f16x8*)&lds[cur][1][aa];
            const int rb = wn * 64 + i * 16 + l15;
            const int ab = rb * 32 + ((lhi ^ ((rb >> 1) & 3)) * 8);
            fbh[i] = *(const f16x8*)&lds[cur][2][ab];
            fbl[i] = *(const f16x8*)&lds[cur][3][ab];
        }
        #pragma unroll
        for (int mi = 0; mi < 4; ++mi)
            #pragma unroll
            for (int ni = 0; ni < 4; ++ni) {
                acc[mi][ni] = MFMA16(fah[mi], fbh[ni], acc[mi][ni]);
                acc[mi][ni] = MFMA16(fah[mi], fbl[ni], acc[mi][ni]);
                acc[mi][ni] = MFMA16(fal[mi], fbh[ni], acc[mi][ni]);
            }
        if (ks < 31) WRITE(cur ^ 1);
        __syncthreads();
        cur ^= 1;
    }

    #pragma unroll
    for (int ni = 0; ni < 4; ++ni) {
        const int n = n0 + wn * 64 + ni * 16 + l15;
        const int mat = n >> 10, nn = n & 1023;
        const int h = nn >> 6, e = nn & 63;
        const float bias = (mat == 0 ? bq : mat == 1 ? bk : bv)[h * 64 + e];
        #pragma unroll
        for (int mi = 0; mi < 4; ++mi)
            #pragma unroll
            for (int r = 0; r < 4; ++r) {
                const int m = m0 + wm * 64 + mi * 16 + lhi * 4 + r;
                const int b = m >> 11, s = m & 2047;
                const int bh_i = b * 16 + h;
                const float v = acc[mi][ni][r] + bias;
                if (mat == 2) {
                    ovT[((size_t)bh_i * 64 + e) * 2048 + s] = (half_t)v;
                } else {
                    half_t hh, hl; split2(v, hh, hl);
                    const size_t o = ((size_t)bh_i * 2048 + s) * 64 + e;
                    if (mat == 0) { oqh[o] = hh; oql[o] = hl; }
                    else          { okh[o] = hh; okl[o] = hl; }
                }
            }
    }
}

// ---------------------------------------------------------------------------
// QK^T (3-pass fp16-split) + causal mask; raw fp32 scores -> pattern buffer;
// online per-row (m, l).
// ---------------------------------------------------------------------------
__global__ __launch_bounds__(256) void k_qk(
    const half_t* __restrict__ qh, const half_t* __restrict__ ql,
    const half_t* __restrict__ kh, const half_t* __restrict__ kl,
    float* __restrict__ pattern, float* __restrict__ mws, float* __restrict__ lws)
{
    __shared__ half_t lds[2][2][64 * 64];
    const int qt = 31 - blockIdx.x, bh = blockIdx.y;
    const int tid = threadIdx.x, w = tid >> 6, lane = tid & 63;
    const int l15 = lane & 15, lhi = lane >> 4;
    const int rw = qt * 64 + w * 16;

    const size_t qrow = ((size_t)bh * 2048 + rw + l15) * 64;
    f16x8 aqh[2], aql[2];
    #pragma unroll
    for (int ch = 0; ch < 2; ++ch) {
        aqh[ch] = *(const f16x8*)&qh[qrow + ch * 32 + lhi * 8];
        aql[ch] = *(const f16x8*)&ql[qrow + ch * 32 + lhi * 8];
    }

    const int sr0 = w * 16 + (lane >> 3);
    const int sr1 = sr0 + 8;
    const int su  = lane & 7;
    const size_t kbase = (size_t)bh * 2048 * 64;
    const int sd0 = sr0 * 64 + ((su ^ (sr0 & 7)) * 8);
    const int sd1 = sr1 * 64 + ((su ^ (sr1 & 7)) * 8);

    int4 st[4];
    auto LOADK = [&](int kt) {
        const size_t g0 = kbase + (size_t)(kt * 64 + sr0) * 64 + su * 8;
        const size_t g1 = kbase + (size_t)(kt * 64 + sr1) * 64 + su * 8;
        st[0] = *(const int4*)&kh[g0];
        st[1] = *(const int4*)&kh[g1];
        st[2] = *(const int4*)&kl[g0];
        st[3] = *(const int4*)&kl[g1];
    };
    auto WRITEK = [&](int bf) {
        *(int4*)&lds[bf][0][sd0] = st[0];
        *(int4*)&lds[bf][0][sd1] = st[1];
        *(int4*)&lds[bf][1][sd0] = st[2];
        *(int4*)&lds[bf][1][sd1] = st[3];
    };

    float m[4], l[4];
    #pragma unroll
    for (int r = 0; r < 4; ++r) { m[r] = -1e30f; l[r] = 0.f; }

    LOADK(0); WRITEK(0); __syncthreads();
    int cur = 0;
    for (int kt = 0; kt <= qt; ++kt) {
        if (kt < qt) LOADK(kt + 1);
        f32x4 acc[4] = {};
        #pragma unroll
        for (int nt = 0; nt < 4; ++nt) {
            const int kr = nt * 16 + l15;
            #pragma unroll
            for (int ch = 0; ch < 2; ++ch) {
                const int slot = ch * 4 + lhi;
                const int ad = kr * 64 + ((slot ^ (kr & 7)) * 8);
                f16x8 bh8 = *(const f16x8*)&lds[cur][0][ad];
                f16x8 bl8 = *(const f16x8*)&lds[cur][1][ad];
                acc[nt] = MFMA16(aqh[ch], bh8, acc[nt]);
                acc[nt] = MFMA16(aqh[ch], bl8, acc[nt]);
                acc[nt] = MFMA16(aql[ch], bh8, acc[nt]);
            }
        }
        float tmax[4] = {-1e30f, -1e30f, -1e30f, -1e30f};
        const bool diag = (kt == qt);
        #pragma unroll
        for (int nt = 0; nt < 4; ++nt) {
            const int key = kt * 64 + nt * 16 + l15;
            #pragma unroll
            for (int r = 0; r < 4; ++r) {
                float s = acc[nt][r] * 0.125f;
                const int row = rw + lhi * 4 + r;
                if (diag && key > row) s = -1e30f;
                acc[nt][r] = s;
                tmax[r] = fmaxf(tmax[r], s);
            }
        }
        #pragma unroll
        for (int nt = 0; nt < 4; ++nt) {
            const int key = kt * 64 + nt * 16 + l15;
            const size_t pb = ((size_t)bh * 2048 + rw + lhi * 4) * 2048 + key;
            #pragma unroll
            for (int r = 0; r < 4; ++r)
                pattern[pb + (size_t)r * 2048] = acc[nt][r];
        }
        #pragma unroll
        for (int off = 1; off < 16; off <<= 1)
            #pragma unroll
            for (int r = 0; r < 4; ++r)
                tmax[r] = fmaxf(tmax[r], __shfl_xor(tmax[r], off));
        #pragma unroll
        for (int r = 0; r < 4; ++r) {
            const float mn = fmaxf(m[r], tmax[r]);
            l[r] *= __expf(m[r] - mn);
            m[r] = mn;
        }
        float esum[4] = {0.f, 0.f, 0.f, 0.f};
        #pragma unroll
        for (int nt = 0; nt < 4; ++nt)
            #pragma unroll
            for (int r = 0; r < 4; ++r)
                esum[r] += __expf(acc[nt][r] - m[r]);
        #pragma unroll
        for (int off = 1; off < 16; off <<= 1)
            #pragma unroll
            for (int r = 0; r < 4; ++r)
                esum[r] += __shfl_xor(esum[r], off);
        #pragma unroll
        for (int r = 0; r < 4; ++r) l[r] += esum[r];

        if (kt < qt) WRITEK(cur ^ 1);
        __syncthreads();
        cur ^= 1;
    }

    if (l15 == 0) {
        #pragma unroll
        for (int r = 0; r < 4; ++r) {
            const int row = rw + lhi * 4 + r;
            mws[bh * 2048 + row] = m[r];
            lws[bh * 2048 + row] = l[r];
        }
    }
}

// ---------------------------------------------------------------------------
// PV finalize: coalesced pattern read/normalize/write + zero-fill; P tile
// bounced through swizzled LDS into MFMA A-fragments; z = P*V via fp16 MFMA.
// grid (32 qt, 64 bh), 4 waves.
// ---------------------------------------------------------------------------
__global__ __launch_bounds__(256) void k_pv(
    const half_t* __restrict__ vT,
    const float* __restrict__ mws, const float* __restrict__ lws,
    float* __restrict__ pattern, half_t* __restrict__ z)
{
    const int qt = blockIdx.x, bh = blockIdx.y;
    const int b = bh >> 4, h = bh & 15;
    const int tid = threadIdx.x, w = tid >> 6, lane = tid & 63;
    const int l15 = lane & 15, lhi = lane >> 4;
    const int q0 = qt * 64;

    __shared__ half_t pa[64 * 64];     // swizzled fp16 P tile (A operand)
    __shared__ float mrow[64], irow[64];

    if (tid < 64) {
        mrow[tid] = mws[bh * 2048 + q0 + tid];
        irow[tid] = 1.f / lws[bh * 2048 + q0 + tid];
    }
    __syncthreads();

    // streaming slots: thread covers rows {rep*16 + (tid>>4)}, col (tid&15)*4
    const int r_    = tid >> 4;
    const int c0    = (tid & 15) * 4;
    const int chunk = c0 >> 3;
    const int cin   = c0 & 7;

    f32x4 acc[4] = {};
    const size_t prow_base = ((size_t)bh * 2048 + q0) * 2048;
    const int arow = w * 16 + l15;

    for (int kt = 0; kt < 32; ++kt) {
        if (kt <= qt) {
            #pragma unroll
            for (int rep = 0; rep < 4; ++rep) {
                const int row = rep * 16 + r_;
                const size_t go = prow_base + (size_t)row * 2048 + kt * 64 + c0;
                float4 s = *(const float4*)&pattern[go];
                const float m0 = mrow[row], iv = irow[row];
                float4 p;
                p.x = __expf(s.x - m0) * iv;
                p.y = __expf(s.y - m0) * iv;
                p.z = __expf(s.z - m0) * iv;
                p.w = __expf(s.w - m0) * iv;
                *(float4*)&pattern[go] = p;
                f16x4 ph;
                ph[0] = (half_t)p.x; ph[1] = (half_t)p.y;
                ph[2] = (half_t)p.z; ph[3] = (half_t)p.w;
                *(f16x4*)&pa[row * 64 + ((chunk ^ (row & 7)) * 8) + cin] = ph;
            }
            __syncthreads();
            #pragma unroll
            for (int ch = 0; ch < 2; ++ch) {
                const int slot = ch * 4 + lhi;
                f16x8 af = *(const f16x8*)&pa[arow * 64 + ((slot ^ (arow & 7)) * 8)];
                #pragma unroll
                for (int nt = 0; nt < 4; ++nt) {
                    f16x8 bf8 = *(const f16x8*)&vT[((size_t)bh * 64 + nt * 16 + l15) * 2048
                                                   + kt * 64 + ch * 32 + lhi * 8];
                    acc[nt] = MFMA16(af, bf8, acc[nt]);
                }
            }
            __syncthreads();
        } else {
            float4 zz; zz.x = 0.f; zz.y = 0.f; zz.z = 0.f; zz.w = 0.f;
            #pragma unroll
            for (int rep = 0; rep < 4; ++rep) {
                const int row = rep * 16 + r_;
                *(float4*)&pattern[prow_base + (size_t)row * 2048 + kt * 64 + c0] = zz;
            }
        }
    }

    const int rw = q0 + w * 16;
    #pragma unroll
    for (int nt = 0; nt < 4; ++nt) {
        const int e = nt * 16 + l15;
        #pragma unroll
        for (int r = 0; r < 4; ++r) {
            const int row = rw + lhi * 4 + r;
            z[((size_t)(b * 2048 + row)) * 1024 + h * 64 + e] = (half_t)acc[nt][r];
        }
    }
}

// ---------------------------------------------------------------------------
// O projection GEMM: M=8192, N=1024, K=1024, 1-pass fp16 MFMA.
// ---------------------------------------------------------------------------
__global__ __launch_bounds__(256) void k_oproj(
    const half_t* __restrict__ z, const half_t* __restrict__ woT,
    const float* __restrict__ bo, float* __restrict__ out)
{
    __shared__ half_t lds[2][2][128 * 32];
    const int tid = threadIdx.x, w = tid >> 6, lane = tid & 63;
    const int l15 = lane & 15, lhi = lane >> 4;
    const int wm = w >> 1, wn = w & 1;
    const int m0 = blockIdx.y * 128, n0 = blockIdx.x * 128;

    const int r0 = w * 32 + (lane >> 2);
    const int r1 = r0 + 16;
    const int u  = lane & 3;
    const size_t gA0 = (size_t)(m0 + r0) * 1024 + u * 8;
    const size_t gA1 = (size_t)(m0 + r1) * 1024 + u * 8;
    const size_t gB0 = (size_t)(n0 + r0) * 1024 + u * 8;
    const size_t gB1 = (size_t)(n0 + r1) * 1024 + u * 8;
    const int d0 = r0 * 32 + ((u ^ ((r0 >> 1) & 3)) * 8);
    const int d1 = r1 * 32 + ((u ^ ((r1 >> 1) & 3)) * 8);

    int4 st[4];
    auto LOAD = [&](int kb) {
        st[0] = *(const int4*)&z[gA0 + kb];
        st[1] = *(const int4*)&z[gA1 + kb];
        st[2] = *(const int4*)&woT[gB0 + kb];
        st[3] = *(const int4*)&woT[gB1 + kb];
    };
    auto WRITE = [&](int bf) {
        *(int4*)&lds[bf][0][d0] = st[0];
        *(int4*)&lds[bf][0][d1] = st[1];
        *(int4*)&lds[bf][1][d0] = st[2];
        *(int4*)&lds[bf][1][d1] = st[3];
    };

    f32x4 acc[4][4] = {};
    LOAD(0); WRITE(0); __syncthreads();
    int cur = 0;
    for (int ks = 0; ks < 32; ++ks) {
        if (ks < 31) LOAD((ks + 1) * 32);
        f16x8 fa[4], fb[4];
        #pragma unroll
        for (int i = 0; i < 4; ++i) {
            const int ra = wm * 64 + i * 16 + l15;
            fa[i] = *(const f16x8*)&lds[cur][0][ra * 32 + ((lhi ^ ((ra >> 1) & 3)) * 8)];
            const int rb = wn * 64 + i * 16 + l15;
            fb[i] = *(const f16x8*)&lds[cur][1][rb * 32 + ((lhi ^ ((rb >> 1) & 3)) * 8)];
        }
        #pragma unroll
        for (int mi = 0; mi < 4; ++mi)
            #pragma unroll
            for (int ni = 0; ni < 4; ++ni)
                acc[mi][ni] = MFMA16(fa[mi], fb[ni], acc[mi][ni]);
        if (ks < 31) WRITE(cur ^ 1);
        __syncthreads();
        cur ^= 1;
    }

    #pragma unroll
    for (int ni = 0; ni < 4; ++ni) {
        const int n = n0 + wn * 64 + ni * 16 + l15;
        const float bb = bo[n];
        #pragma unroll
        for (int mi = 0; mi < 4; ++mi)
            #pragma unroll
            for (int r = 0; r < 4; ++r) {
                const int m = m0 + wm * 64 + mi * 16 + lhi * 4 + r;
                out[(size_t)m * 1024 + n] = acc[mi][ni][r] + bb;
            }
    }
}

// ---------------------------------------------------------------------------
extern "C" void kernel_launch(void* const* d_in, const int* in_sizes, int n_in,
                              void* d_out, int out_size, void* d_ws, size_t ws_size,
                              hipStream_t stream) {
    const float* x  = (const float*)d_in[0];
    const float* Wq = (const float*)d_in[1];
    const float* bq = (const float*)d_in[2];
    const float* Wk = (const float*)d_in[3];
    const float* bk = (const float*)d_in[4];
    const float* Wv = (const float*)d_in[5];
    const float* bv = (const float*)d_in[6];
    const float* Wo = (const float*)d_in[7];
    const float* bo = (const float*)d_in[8];

    float* out      = (float*)d_out;
    float* attn_out = out;
    float* pattern  = out + (size_t)8192 * 1024;

    char* wsb = (char*)d_ws;
    const size_t M16 = 16777216;
    half_t* qh  = (half_t*)(wsb + 0 * M16);
    half_t* ql  = (half_t*)(wsb + 1 * M16);
    half_t* kh  = (half_t*)(wsb + 2 * M16);
    half_t* kl  = (half_t*)(wsb + 3 * M16);
    half_t* vT  = (half_t*)(wsb + 4 * M16);
    half_t* xh  = (half_t*)(wsb + 5 * M16);
    half_t* xl  = (half_t*)(wsb + 6 * M16);
    half_t* wh  = (half_t*)(wsb + 7 * M16);                 // 6 MiB
    half_t* wl  = (half_t*)(wsb + 7 * M16 + 6291456);       // 6 MiB
    half_t* woT = (half_t*)(wsb + 7 * M16 + 12582912);      // 2 MiB
    half_t* zbuf = xh;                                      // alias, dead after k_proj
    float*  mws  = (float*)xl;
    float*  lws  = (float*)(wsb + 6 * M16 + 524288);

    k_conv_x <<<4096, 256, 0, stream>>>(x, xh, xl);
    k_conv_w <<<768,  256, 0, stream>>>(Wq, Wk, Wv, wh, wl);
    k_conv_wo<<<256,  256, 0, stream>>>(Wo, woT);
    k_proj   <<<dim3(24, 64), 256, 0, stream>>>(xh, xl, wh, wl, bq, bk, bv,
                                                qh, ql, kh, kl, vT);
    k_qk     <<<dim3(32, 64), 256, 0, stream>>>(qh, ql, kh, kl, pattern, mws, lws);
    k_pv     <<<dim3(32, 64), 256, 0, stream>>>(vT, mws, lws, pattern, zbuf);
    k_oproj  <<<dim3(8, 64),  256, 0, stream>>>(zbuf, woT, bo, attn_out);
}

// Round 5
// 1432.026 us; speedup vs baseline: 2.0584x; 1.0781x over previous
//
#include <hip/hip_runtime.h>
#include <hip/hip_bf16.h>

// B=4, S=2048, D_MODEL=1024, H=16, E=64, M=8192 rows, bh = b*16+h (64)
// Precision: fp32 value = hi + lo (2x fp16, ~24 mantissa bits, fp32-exact).
// Products via 3 MFMA passes (hh, hl, lh); ll ~ 2^-24 rel -> dropped.
// V path and PV/O GEMMs: single-pass fp16 (error << thresholds).
// MFMA shape: mfma_f32_16x16x32_f16.
//   A-frag: lane l holds A[m=l&15][k=(l>>4)*8+j]  (16B contiguous)
//   B-frag: lane l holds B[k=(l>>4)*8+j][n=l&15]  (read from [n][k]-major array)
//   C/D  : lane l holds D[row=(l>>4)*4+r][col=l&15]

typedef _Float16 half_t;
typedef __attribute__((ext_vector_type(8))) _Float16 f16x8;
typedef __attribute__((ext_vector_type(4))) _Float16 f16x4;
typedef __attribute__((ext_vector_type(4))) float f32x4;

#define MFMA16(a, b, c) __builtin_amdgcn_mfma_f32_16x16x32_f16(a, b, c, 0, 0, 0)

__device__ __forceinline__ void split2(float v, half_t& h, half_t& l) {
    h = (half_t)v;
    l = (half_t)(v - (float)h);
}

// ---------------------------------------------------------------------------
// x [8192][1024] fp32 -> xh, xl fp16 planes
// ---------------------------------------------------------------------------
__global__ __launch_bounds__(256) void k_conv_x(
    const float* __restrict__ x, half_t* __restrict__ xh, half_t* __restrict__ xl)
{
    const size_t i = ((size_t)blockIdx.x * 256 + threadIdx.x) * 8;
    float4 a = *(const float4*)&x[i];
    float4 b = *(const float4*)&x[i + 4];
    float v[8] = {a.x, a.y, a.z, a.w, b.x, b.y, b.z, b.w};
    f16x8 H, L;
    #pragma unroll
    for (int j = 0; j < 8; ++j) {
        half_t hh, hl; split2(v[j], hh, hl);
        H[j] = hh; L[j] = hl;
    }
    *(f16x8*)&xh[i] = H;
    *(f16x8*)&xl[i] = L;
}

// ---------------------------------------------------------------------------
// W_{Q,K,V} [16][1024 d][64 e] fp32 -> wh, wl fp16 [n=3072][k=1024] (transposed)
// ---------------------------------------------------------------------------
__global__ __launch_bounds__(256) void k_conv_w(
    const float* __restrict__ Wq, const float* __restrict__ Wk, const float* __restrict__ Wv,
    half_t* __restrict__ wh, half_t* __restrict__ wl)
{
    const int bid = blockIdx.x;
    const int mat = bid >> 8, h = (bid >> 4) & 15, dt = bid & 15;
    const float* W = (mat == 0) ? Wq : (mat == 1) ? Wk : Wv;
    __shared__ float t[64][65];
    const int tid = threadIdx.x;
    #pragma unroll
    for (int rep = 0; rep < 4; ++rep) {
        int idx = tid + rep * 256;
        int r = idx >> 4, c4 = (idx & 15) * 4;
        float4 v4 = *(const float4*)&W[(size_t)h * 65536 + (size_t)(dt * 64 + r) * 64 + c4];
        t[r][c4 + 0] = v4.x; t[r][c4 + 1] = v4.y;
        t[r][c4 + 2] = v4.z; t[r][c4 + 3] = v4.w;
    }
    __syncthreads();
    #pragma unroll
    for (int rep = 0; rep < 4; ++rep) {
        int idx = tid + rep * 256;
        int e = idx >> 4, g = (idx & 15) * 4;
        size_t o = ((size_t)(mat * 1024 + h * 64 + e)) * 1024 + dt * 64 + g;
        #pragma unroll
        for (int j = 0; j < 4; ++j) {
            half_t hh, hl; split2(t[g + j][e], hh, hl);
            wh[o + j] = hh; wl[o + j] = hl;
        }
    }
}

// W_O [1024 hd][1024 dm] fp32 -> woT fp16 [dm][hd]
__global__ __launch_bounds__(256) void k_conv_wo(
    const float* __restrict__ Wo, half_t* __restrict__ woT)
{
    const int bi = blockIdx.x >> 4, bj = blockIdx.x & 15;
    __shared__ float t[64][65];
    const int tid = threadIdx.x;
    #pragma unroll
    for (int rep = 0; rep < 4; ++rep) {
        int idx = tid + rep * 256;
        int r = idx >> 4, c4 = (idx & 15) * 4;
        float4 v4 = *(const float4*)&Wo[(size_t)(bi * 64 + r) * 1024 + bj * 64 + c4];
        t[r][c4 + 0] = v4.x; t[r][c4 + 1] = v4.y;
        t[r][c4 + 2] = v4.z; t[r][c4 + 3] = v4.w;
    }
    __syncthreads();
    #pragma unroll
    for (int rep = 0; rep < 4; ++rep) {
        int idx = tid + rep * 256;
        int dm = idx >> 4, g = (idx & 15) * 4;
        size_t o = (size_t)(bj * 64 + dm) * 1024 + bi * 64 + g;
        #pragma unroll
        for (int j = 0; j < 4; ++j)
            woT[o + j] = (half_t)t[g + j][dm];
    }
}

// ---------------------------------------------------------------------------
// QKV projection GEMM: M=8192, N=3072, K=1024.
// Q/K n-blocks: 3-pass fp16-split; V n-blocks (n0>=2048): 1-pass.
// ---------------------------------------------------------------------------
__global__ __launch_bounds__(256) void k_proj(
    const half_t* __restrict__ xh, const half_t* __restrict__ xl,
    const half_t* __restrict__ wh, const half_t* __restrict__ wl,
    const float* __restrict__ bq, const float* __restrict__ bk, const float* __restrict__ bv,
    half_t* __restrict__ oqh, half_t* __restrict__ oql,
    half_t* __restrict__ okh, half_t* __restrict__ okl,
    half_t* __restrict__ ovT)
{
    __shared__ half_t lds[2][4][128 * 32];
    const int tid = threadIdx.x, w = tid >> 6, lane = tid & 63;
    const int l15 = lane & 15, lhi = lane >> 4;
    const int wm = w >> 1, wn = w & 1;
    const int m0 = blockIdx.y * 128, n0 = blockIdx.x * 128;
    const bool isv = (n0 >= 2048);          // V block: single-pass

    const int r0 = w * 32 + (lane >> 2);
    const int r1 = r0 + 16;
    const int u  = lane & 3;
    const size_t gA0 = (size_t)(m0 + r0) * 1024 + u * 8;
    const size_t gA1 = (size_t)(m0 + r1) * 1024 + u * 8;
    const size_t gB0 = (size_t)(n0 + r0) * 1024 + u * 8;
    const size_t gB1 = (size_t)(n0 + r1) * 1024 + u * 8;
    const int d0 = r0 * 32 + ((u ^ ((r0 >> 1) & 3)) * 8);
    const int d1 = r1 * 32 + ((u ^ ((r1 >> 1) & 3)) * 8);

    int4 st[8];
    auto LOAD = [&](int kb) {
        st[0] = *(const int4*)&xh[gA0 + kb];
        st[1] = *(const int4*)&xh[gA1 + kb];
        st[4] = *(const int4*)&wh[gB0 + kb];
        st[5] = *(const int4*)&wh[gB1 + kb];
        if (!isv) {
            st[2] = *(const int4*)&xl[gA0 + kb];
            st[3] = *(const int4*)&xl[gA1 + kb];
            st[6] = *(const int4*)&wl[gB0 + kb];
            st[7] = *(const int4*)&wl[gB1 + kb];
        }
    };
    auto WRITE = [&](int bf) {
        *(int4*)&lds[bf][0][d0] = st[0];
        *(int4*)&lds[bf][0][d1] = st[1];
        *(int4*)&lds[bf][2][d0] = st[4];
        *(int4*)&lds[bf][2][d1] = st[5];
        if (!isv) {
            *(int4*)&lds[bf][1][d0] = st[2];
            *(int4*)&lds[bf][1][d1] = st[3];
            *(int4*)&lds[bf][3][d0] = st[6];
            *(int4*)&lds[bf][3][d1] = st[7];
        }
    };

    f32x4 acc[4][4] = {};

    LOAD(0); WRITE(0); __syncthreads();
    int cur = 0;
    for (int ks = 0; ks < 32; ++ks) {
        if (ks < 31) LOAD((ks + 1) * 32);
        f16x8 fah[4], fal[4], fbh[4], fbl[4];
        #pragma unroll
        for (int i = 0; i < 4; ++i) {
            const int ra = wm * 64 + i * 16 + l15;
            const int aa = ra * 32 + ((lhi ^ ((ra >> 1) & 3)) * 8);
            fah[i] = *(const f16x8*)&lds[cur][0][aa];
            const int rb = wn * 64 + i * 16 + l15;
            const int ab = rb * 32 + ((lhi ^ ((rb >> 1) & 3)) * 8);
            fbh[i] = *(const f16x8*)&lds[cur][2][ab];
            if (!isv) {
                fal[i] = *(const f16x8*)&lds[cur][1][aa];
                fbl[i] = *(const f16x8*)&lds[cur][3][ab];
            }
        }
        if (isv) {
            #pragma unroll
            for (int mi = 0; mi < 4; ++mi)
                #pragma unroll
                for (int ni = 0; ni < 4; ++ni)
                    acc[mi][ni] = MFMA16(fah[mi], fbh[ni], acc[mi][ni]);
        } else {
            #pragma unroll
            for (int mi = 0; mi < 4; ++mi)
                #pragma unroll
                for (int ni = 0; ni < 4; ++ni) {
                    acc[mi][ni] = MFMA16(fah[mi], fbh[ni], acc[mi][ni]);
                    acc[mi][ni] = MFMA16(fah[mi], fbl[ni], acc[mi][ni]);
                    acc[mi][ni] = MFMA16(fal[mi], fbh[ni], acc[mi][ni]);
                }
        }
        if (ks < 31) WRITE(cur ^ 1);
        __syncthreads();
        cur ^= 1;
    }

    #pragma unroll
    for (int ni = 0; ni < 4; ++ni) {
        const int n = n0 + wn * 64 + ni * 16 + l15;
        const int mat = n >> 10, nn = n & 1023;
        const int h = nn >> 6, e = nn & 63;
        const float bias = (mat == 0 ? bq : mat == 1 ? bk : bv)[h * 64 + e];
        #pragma unroll
        for (int mi = 0; mi < 4; ++mi)
            #pragma unroll
            for (int r = 0; r < 4; ++r) {
                const int m = m0 + wm * 64 + mi * 16 + lhi * 4 + r;
                const int b = m >> 11, s = m & 2047;
                const int bh_i = b * 16 + h;
                const float v = acc[mi][ni][r] + bias;
                if (mat == 2) {
                    ovT[((size_t)bh_i * 64 + e) * 2048 + s] = (half_t)v;
                } else {
                    half_t hh, hl; split2(v, hh, hl);
                    const size_t o = ((size_t)bh_i * 2048 + s) * 64 + e;
                    if (mat == 0) { oqh[o] = hh; oql[o] = hl; }
                    else          { okh[o] = hh; okl[o] = hl; }
                }
            }
    }
}

// ---------------------------------------------------------------------------
// Fused attention: per (qt, bh) block of 64 q-rows.
// Phase 1: QK^T 3-pass MFMA; p_t = exp(s - m_tile) stored fp16 to ws blob
//          (LDS-bounced, coalesced); per-tile row max in LDS; online (m,l).
// Phase 2: read blob, scale by exp(m_t - m)*inv_l, write fp32 pattern
//          coalesced (+ zero-fill above diagonal), PV via fp16 MFMA -> z.
// ---------------------------------------------------------------------------
__global__ __launch_bounds__(256) void k_attn(
    const half_t* __restrict__ qh, const half_t* __restrict__ ql,
    const half_t* __restrict__ kh, const half_t* __restrict__ kl,
    const half_t* __restrict__ vT,
    half_t* __restrict__ blob,
    float* __restrict__ pattern, half_t* __restrict__ z)
{
    __shared__ half_t kst[2][2][64 * 64];   // K hi/lo staging (32 KB)
    __shared__ half_t pa[64 * 68];          // bounce tile, padded (8.5 KB)
    __shared__ float mt[32][64];            // per-tile row maxes (8 KB)
    __shared__ float mfin[64], ifin[64];

    const int qt = 31 - blockIdx.x, bh = blockIdx.y;
    const int b = bh >> 4, h = bh & 15;
    const int tid = threadIdx.x, w = tid >> 6, lane = tid & 63;
    const int l15 = lane & 15, lhi = lane >> 4;
    const int q0 = qt * 64, rw = q0 + w * 16;

    half_t* myblob = blob + ((size_t)bh * 528 + ((size_t)qt * (qt + 1)) / 2) * 4096;

    // Q fragments
    const size_t qrow = ((size_t)bh * 2048 + rw + l15) * 64;
    f16x8 aqh[2], aql[2];
    #pragma unroll
    for (int ch = 0; ch < 2; ++ch) {
        aqh[ch] = *(const f16x8*)&qh[qrow + ch * 32 + lhi * 8];
        aql[ch] = *(const f16x8*)&ql[qrow + ch * 32 + lhi * 8];
    }

    // K staging (swizzled): wave w covers key-rows w*16..+16
    const int sr0 = w * 16 + (lane >> 3);
    const int sr1 = sr0 + 8;
    const int su  = lane & 7;
    const size_t kbase = (size_t)bh * 2048 * 64;
    const int sd0 = sr0 * 64 + ((su ^ (sr0 & 7)) * 8);
    const int sd1 = sr1 * 64 + ((su ^ (sr1 & 7)) * 8);

    int4 st[4];
    auto LOADK = [&](int kt) {
        const size_t g0 = kbase + (size_t)(kt * 64 + sr0) * 64 + su * 8;
        const size_t g1 = kbase + (size_t)(kt * 64 + sr1) * 64 + su * 8;
        st[0] = *(const int4*)&kh[g0];
        st[1] = *(const int4*)&kh[g1];
        st[2] = *(const int4*)&kl[g0];
        st[3] = *(const int4*)&kl[g1];
    };
    auto WRITEK = [&](int bf) {
        *(int4*)&kst[bf][0][sd0] = st[0];
        *(int4*)&kst[bf][0][sd1] = st[1];
        *(int4*)&kst[bf][1][sd0] = st[2];
        *(int4*)&kst[bf][1][sd1] = st[3];
    };

    float m[4], l[4];
    #pragma unroll
    for (int r = 0; r < 4; ++r) { m[r] = -1e30f; l[r] = 0.f; }

    LOADK(0); WRITEK(0); __syncthreads();
    int cur = 0;
    for (int kt = 0; kt <= qt; ++kt) {
        if (kt < qt) LOADK(kt + 1);
        f32x4 acc[4] = {};
        #pragma unroll
        for (int nt = 0; nt < 4; ++nt) {
            const int kr = nt * 16 + l15;
            #pragma unroll
            for (int ch = 0; ch < 2; ++ch) {
                const int slot = ch * 4 + lhi;
                const int ad = kr * 64 + ((slot ^ (kr & 7)) * 8);
                f16x8 bh8 = *(const f16x8*)&kst[cur][0][ad];
                f16x8 bl8 = *(const f16x8*)&kst[cur][1][ad];
                acc[nt] = MFMA16(aqh[ch], bh8, acc[nt]);
                acc[nt] = MFMA16(aqh[ch], bl8, acc[nt]);
                acc[nt] = MFMA16(aql[ch], bh8, acc[nt]);
            }
        }
        // scale + causal mask + tile row-max
        float tmax[4] = {-1e30f, -1e30f, -1e30f, -1e30f};
        const bool diag = (kt == qt);
        #pragma unroll
        for (int nt = 0; nt < 4; ++nt) {
            const int key = kt * 64 + nt * 16 + l15;
            #pragma unroll
            for (int r = 0; r < 4; ++r) {
                float s = acc[nt][r] * 0.125f;
                const int row = rw + lhi * 4 + r;
                if (diag && key > row) s = -1e30f;
                acc[nt][r] = s;
                tmax[r] = fmaxf(tmax[r], s);
            }
        }
        #pragma unroll
        for (int off = 1; off < 16; off <<= 1)
            #pragma unroll
            for (int r = 0; r < 4; ++r)
                tmax[r] = fmaxf(tmax[r], __shfl_xor(tmax[r], off));

        // p relative to tile max -> LDS bounce; esum
        float esum[4] = {0.f, 0.f, 0.f, 0.f};
        #pragma unroll
        for (int nt = 0; nt < 4; ++nt)
            #pragma unroll
            for (int r = 0; r < 4; ++r) {
                const float p = __expf(acc[nt][r] - tmax[r]);
                esum[r] += p;
                pa[(w * 16 + lhi * 4 + r) * 68 + nt * 16 + l15] = (half_t)p;
            }
        if (l15 == 0) {
            #pragma unroll
            for (int r = 0; r < 4; ++r)
                mt[kt][w * 16 + lhi * 4 + r] = tmax[r];
        }
        #pragma unroll
        for (int off = 1; off < 16; off <<= 1)
            #pragma unroll
            for (int r = 0; r < 4; ++r)
                esum[r] += __shfl_xor(esum[r], off);
        #pragma unroll
        for (int r = 0; r < 4; ++r) {
            const float mn = fmaxf(m[r], tmax[r]);
            l[r] = l[r] * __expf(m[r] - mn) + esum[r] * __expf(tmax[r] - mn);
            m[r] = mn;
        }
        __syncthreads();
        // stream pa -> blob, coalesced
        #pragma unroll
        for (int rep = 0; rep < 2; ++rep) {
            const int i = rep * 2048 + tid * 8;
            const int row = i >> 6, col = i & 63;
            *(f16x8*)&myblob[(size_t)kt * 4096 + i] = *(const f16x8*)&pa[row * 68 + col];
        }
        if (kt < qt) WRITEK(cur ^ 1);
        __syncthreads();
        cur ^= 1;
    }

    // final m, 1/l to LDS
    if (l15 == 0) {
        #pragma unroll
        for (int r = 0; r < 4; ++r) {
            mfin[w * 16 + lhi * 4 + r] = m[r];
            ifin[w * 16 + lhi * 4 + r] = 1.f / l[r];
        }
    }
    __syncthreads();

    // ---- Phase 2 ----
    const int r_    = tid >> 4;
    const int c0    = (tid & 15) * 4;
    const int chunk = c0 >> 3;
    const int cin   = c0 & 7;
    const int arow  = w * 16 + l15;
    const size_t prow_base = ((size_t)bh * 2048 + q0) * 2048;

    f32x4 acc2[4] = {};
    for (int kt = 0; kt < 32; ++kt) {
        if (kt <= qt) {
            #pragma unroll
            for (int rep = 0; rep < 4; ++rep) {
                const int row = rep * 16 + r_;
                f16x4 pv4 = *(const f16x4*)&myblob[(size_t)kt * 4096 + row * 64 + c0];
                const float fac = __expf(mt[kt][row] - mfin[row]) * ifin[row];
                float4 p;
                p.x = (float)pv4[0] * fac;
                p.y = (float)pv4[1] * fac;
                p.z = (float)pv4[2] * fac;
                p.w = (float)pv4[3] * fac;
                *(float4*)&pattern[prow_base + (size_t)row * 2048 + kt * 64 + c0] = p;
                f16x4 ph;
                ph[0] = (half_t)p.x; ph[1] = (half_t)p.y;
                ph[2] = (half_t)p.z; ph[3] = (half_t)p.w;
                *(f16x4*)&pa[row * 64 + ((chunk ^ (row & 7)) * 8) + cin] = ph;
            }
            __syncthreads();
            #pragma unroll
            for (int ch = 0; ch < 2; ++ch) {
                const int slot = ch * 4 + lhi;
                f16x8 af = *(const f16x8*)&pa[arow * 64 + ((slot ^ (arow & 7)) * 8)];
                #pragma unroll
                for (int nt = 0; nt < 4; ++nt) {
                    f16x8 bf8 = *(const f16x8*)&vT[((size_t)bh * 64 + nt * 16 + l15) * 2048
                                                   + kt * 64 + ch * 32 + lhi * 8];
                    acc2[nt] = MFMA16(af, bf8, acc2[nt]);
                }
            }
            __syncthreads();
        } else {
            float4 zz; zz.x = 0.f; zz.y = 0.f; zz.z = 0.f; zz.w = 0.f;
            #pragma unroll
            for (int rep = 0; rep < 4; ++rep) {
                const int row = rep * 16 + r_;
                *(float4*)&pattern[prow_base + (size_t)row * 2048 + kt * 64 + c0] = zz;
            }
        }
    }

    #pragma unroll
    for (int nt = 0; nt < 4; ++nt) {
        const int e = nt * 16 + l15;
        #pragma unroll
        for (int r = 0; r < 4; ++r) {
            const int row = rw + lhi * 4 + r;
            z[((size_t)(b * 2048 + row)) * 1024 + h * 64 + e] = (half_t)acc2[nt][r];
        }
    }
}

// ---------------------------------------------------------------------------
// O projection GEMM: M=8192, N=1024, K=1024, 1-pass fp16 MFMA.
// ---------------------------------------------------------------------------
__global__ __launch_bounds__(256) void k_oproj(
    const half_t* __restrict__ z, const half_t* __restrict__ woT,
    const float* __restrict__ bo, float* __restrict__ out)
{
    __shared__ half_t lds[2][2][128 * 32];
    const int tid = threadIdx.x, w = tid >> 6, lane = tid & 63;
    const int l15 = lane & 15, lhi = lane >> 4;
    const int wm = w >> 1, wn = w & 1;
    const int m0 = blockIdx.y * 128, n0 = blockIdx.x * 128;

    const int r0 = w * 32 + (lane >> 2);
    const int r1 = r0 + 16;
    const int u  = lane & 3;
    const size_t gA0 = (size_t)(m0 + r0) * 1024 + u * 8;
    const size_t gA1 = (size_t)(m0 + r1) * 1024 + u * 8;
    const size_t gB0 = (size_t)(n0 + r0) * 1024 + u * 8;
    const size_t gB1 = (size_t)(n0 + r1) * 1024 + u * 8;
    const int d0 = r0 * 32 + ((u ^ ((r0 >> 1) & 3)) * 8);
    const int d1 = r1 * 32 + ((u ^ ((r1 >> 1) & 3)) * 8);

    int4 st[4];
    auto LOAD = [&](int kb) {
        st[0] = *(const int4*)&z[gA0 + kb];
        st[1] = *(const int4*)&z[gA1 + kb];
        st[2] = *(const int4*)&woT[gB0 + kb];
        st[3] = *(const int4*)&woT[gB1 + kb];
    };
    auto WRITE = [&](int bf) {
        *(int4*)&lds[bf][0][d0] = st[0];
        *(int4*)&lds[bf][0][d1] = st[1];
        *(int4*)&lds[bf][1][d0] = st[2];
        *(int4*)&lds[bf][1][d1] = st[3];
    };

    f32x4 acc[4][4] = {};
    LOAD(0); WRITE(0); __syncthreads();
    int cur = 0;
    for (int ks = 0; ks < 32; ++ks) {
        if (ks < 31) LOAD((ks + 1) * 32);
        f16x8 fa[4], fb[4];
        #pragma unroll
        for (int i = 0; i < 4; ++i) {
            const int ra = wm * 64 + i * 16 + l15;
            fa[i] = *(const f16x8*)&lds[cur][0][ra * 32 + ((lhi ^ ((ra >> 1) & 3)) * 8)];
            const int rb = wn * 64 + i * 16 + l15;
            fb[i] = *(const f16x8*)&lds[cur][1][rb * 32 + ((lhi ^ ((rb >> 1) & 3)) * 8)];
        }
        #pragma unroll
        for (int mi = 0; mi < 4; ++mi)
            #pragma unroll
            for (int ni = 0; ni < 4; ++ni)
                acc[mi][ni] = MFMA16(fa[mi], fb[ni], acc[mi][ni]);
        if (ks < 31) WRITE(cur ^ 1);
        __syncthreads();
        cur ^= 1;
    }

    #pragma unroll
    for (int ni = 0; ni < 4; ++ni) {
        const int n = n0 + wn * 64 + ni * 16 + l15;
        const float bb = bo[n];
        #pragma unroll
        for (int mi = 0; mi < 4; ++mi)
            #pragma unroll
            for (int r = 0; r < 4; ++r) {
                const int m = m0 + wm * 64 + mi * 16 + lhi * 4 + r;
                out[(size_t)m * 1024 + n] = acc[mi][ni][r] + bb;
            }
    }
}

// ---------------------------------------------------------------------------
extern "C" void kernel_launch(void* const* d_in, const int* in_sizes, int n_in,
                              void* d_out, int out_size, void* d_ws, size_t ws_size,
                              hipStream_t stream) {
    const float* x  = (const float*)d_in[0];
    const float* Wq = (const float*)d_in[1];
    const float* bq = (const float*)d_in[2];
    const float* Wk = (const float*)d_in[3];
    const float* bk = (const float*)d_in[4];
    const float* Wv = (const float*)d_in[5];
    const float* bv = (const float*)d_in[6];
    const float* Wo = (const float*)d_in[7];
    const float* bo = (const float*)d_in[8];

    float* out      = (float*)d_out;
    float* attn_out = out;
    float* pattern  = out + (size_t)8192 * 1024;

    char* wsb = (char*)d_ws;
    const size_t M16 = 16777216;
    half_t* qh  = (half_t*)(wsb + 0 * M16);
    half_t* ql  = (half_t*)(wsb + 1 * M16);
    half_t* kh  = (half_t*)(wsb + 2 * M16);
    half_t* kl  = (half_t*)(wsb + 3 * M16);
    half_t* vT  = (half_t*)(wsb + 4 * M16);
    half_t* xh  = (half_t*)(wsb + 5 * M16);
    half_t* xl  = (half_t*)(wsb + 6 * M16);
    half_t* wh  = (half_t*)(wsb + 7 * M16);                 // 6 MiB
    half_t* wl  = (half_t*)(wsb + 7 * M16 + 6291456);       // 6 MiB
    half_t* woT = (half_t*)(wsb + 7 * M16 + 12582912);      // 2 MiB
    half_t* blob = (half_t*)(wsb + 7 * M16 + 14680064);     // 276 MiB (triangular)
    half_t* zbuf = xh;                                      // alias, dead after k_proj

    k_conv_x <<<4096, 256, 0, stream>>>(x, xh, xl);
    k_conv_w <<<768,  256, 0, stream>>>(Wq, Wk, Wv, wh, wl);
    k_conv_wo<<<256,  256, 0, stream>>>(Wo, woT);
    k_proj   <<<dim3(24, 64), 256, 0, stream>>>(xh, xl, wh, wl, bq, bk, bv,
                                                qh, ql, kh, kl, vT);
    k_attn   <<<dim3(32, 64), 256, 0, stream>>>(qh, ql, kh, kl, vT, blob,
                                                pattern, zbuf);
    k_oproj  <<<dim3(8, 64),  256, 0, stream>>>(zbuf, woT, bo, attn_out);
}